// Round 3
// baseline (195.975 us; speedup 1.0000x reference)
//
#include <hip/hip_runtime.h>
#include <hip/hip_bf16.h>
#include <stdint.h>

// Problem: B=8192, E=1024, P=512. x:[8192,2048] f32, w:[1024,512] f32, b:[512] f32.
// out: scalar = mean_i( -S[i,i^4096]/T + log(sum_{j!=i} exp(S[i,j]/T)) ),
// S = zn zn^T (symmetric -> upper triangle of 256x256 blocks), T=0.1.
// Pipeline: prep2 -> gemm1q (fp8 MX, 128^2 R0 structure) -> norm ->
// gemm2 (fp8 MX, 256^2 8-wave 4-phase schedule, supertiled triangle) -> finalize.
//
// R3 (fixes R2's two bugs):
//  - all 8 next-tile stages issued at TILE TOP -> the single end-of-tile
//    vmcnt(0) has ~full-tile (~2200 cyc) cover (R2 issued B panels right
//    before the wait -> stalled every tile).
//  - supertile triangle decode (4x4-block supertiles, 2 MB working set
//    <= 4 MB per-XCD L2; 528 = 8*66 XCD-chunked) replaces the row-major
//    decode that doubled FETCH_SIZE in R2.
// Data layout / swizzle / fragment algebra identical to R2 (verified, absmax 0).
//
// ws layout (bytes):
//   wt8 fp8  [512][1024]    @ 0
//   x8  fp8  [16384][1024]  @ 1048576
//   z   bf16 [16384][512]   @ 17825792
//   zn8 fp8  [8192][1024]   @ 68157440
//   sumexp f32[8192]        @ 84934656
//   pos    f32[8192]        @ 84967424

typedef __attribute__((ext_vector_type(4))) float f32x4;
typedef __attribute__((ext_vector_type(4))) int i32x4;
typedef __attribute__((ext_vector_type(8))) int i32x8;

__device__ __forceinline__ unsigned short f2bf(float f) {
  union { float f; unsigned int u; } v; v.f = f;
  unsigned int u = v.u;
  u += 0x7FFFu + ((u >> 16) & 1u);
  return (unsigned short)(u >> 16);
}

__device__ __forceinline__ float bf2f(unsigned short s) {
  return __uint_as_float(((unsigned int)s) << 16);
}

// ---------------- prep2: x8 = fp8(16*relu(x)); wt8 = fp8(64*w^T); zeros ------
__global__ __launch_bounds__(256) void prep2_kernel(
    const float* __restrict__ x, const float* __restrict__ w,
    unsigned char* __restrict__ x8, unsigned char* __restrict__ wt8,
    float* __restrict__ sumexp, float* __restrict__ out) {
  int tid = blockIdx.x * 256 + threadIdx.x;
  float4 v = ((const float4*)x)[tid];
  int p = __builtin_amdgcn_cvt_pk_fp8_f32(fmaxf(v.x, 0.f) * 16.f,
                                          fmaxf(v.y, 0.f) * 16.f, 0, false);
  p = __builtin_amdgcn_cvt_pk_fp8_f32(fmaxf(v.z, 0.f) * 16.f,
                                      fmaxf(v.w, 0.f) * 16.f, p, true);
  ((int*)x8)[tid] = p;
  if (tid < 512 * 1024) {
    int k = tid & 1023, n = tid >> 10;
    int q = __builtin_amdgcn_cvt_pk_fp8_f32(w[k * 512 + n] * 64.f, 0.f, 0, false);
    wt8[(n << 10) + k] = (unsigned char)(q & 0xFF);
  }
  if (tid < 8192) sumexp[tid] = 0.f;
  if (tid == 0) out[0] = 0.f;
}

// -------- gemm1q: z[16384,512](bf16) = relu(x)@w + b via fp8 MX --------------
// R0-proven: 128x128 tile, BK=128, XOR-swizzled 16 KB LDS/matrix, 2-barrier.
__global__ __launch_bounds__(256) void gemm1q_kernel(
    const unsigned char* __restrict__ x8, const unsigned char* __restrict__ wt8,
    const float* __restrict__ bias, unsigned short* __restrict__ z) {
  __shared__ unsigned char As[16384] __attribute__((aligned(16)));
  __shared__ unsigned char Bs[16384] __attribute__((aligned(16)));
  int b = blockIdx.x;
  int kk = b >> 3;
  int i0 = ((b & 7) * 16 + (kk >> 2)) * 128;
  int n0 = (kk & 3) * 128;

  int tid = threadIdx.x, L = tid & 63, w = tid >> 6;
  int wm = w >> 1, wn = w & 1;
  int l4 = L & 15, q = L >> 4;
  int panel = q * 4096;

  int lp = L ^ ((L >> 3) & 7);
  int srow = w * 32 + (lp >> 1), sh = lp & 1;

  f32x4 acc[4][4];
#pragma unroll
  for (int a = 0; a < 4; ++a)
#pragma unroll
    for (int bq = 0; bq < 4; ++bq) acc[a][bq] = (f32x4)0.f;

  const unsigned char* Ag = x8 + (size_t)(i0 + srow) * 1024 + sh * 16;
  const unsigned char* Bg = wt8 + (size_t)(n0 + srow) * 1024 + sh * 16;

#pragma unroll 1
  for (int k0 = 0; k0 < 1024; k0 += 128) {
    __syncthreads();
#pragma unroll
    for (int t = 0; t < 4; ++t)
      __builtin_amdgcn_global_load_lds(
          (const __attribute__((address_space(1))) void*)(Ag + k0 + t * 32),
          (__attribute__((address_space(3))) void*)(As + t * 4096 + (tid & ~63) * 16),
          16, 0, 0);
#pragma unroll
    for (int t = 0; t < 4; ++t)
      __builtin_amdgcn_global_load_lds(
          (const __attribute__((address_space(1))) void*)(Bg + k0 + t * 32),
          (__attribute__((address_space(3))) void*)(Bs + t * 4096 + (tid & ~63) * 16),
          16, 0, 0);
    __syncthreads();
    i32x8 afr[4];
#pragma unroll
    for (int mt = 0; mt < 4; ++mt) {
      int row = wm * 64 + mt * 16 + l4;
      int p0 = (row * 2) ^ ((row >> 2) & 7);
      i32x4 lo = *(const i32x4*)(As + panel + p0 * 16);
      i32x4 hi = *(const i32x4*)(As + panel + (p0 ^ 1) * 16);
      afr[mt] = (i32x8){lo.x, lo.y, lo.z, lo.w, hi.x, hi.y, hi.z, hi.w};
    }
#pragma unroll
    for (int nt = 0; nt < 4; ++nt) {
      int row = wn * 64 + nt * 16 + l4;
      int p0 = (row * 2) ^ ((row >> 2) & 7);
      i32x4 lo = *(const i32x4*)(Bs + panel + p0 * 16);
      i32x4 hi = *(const i32x4*)(Bs + panel + (p0 ^ 1) * 16);
      i32x8 bfr = (i32x8){lo.x, lo.y, lo.z, lo.w, hi.x, hi.y, hi.z, hi.w};
#pragma unroll
      for (int mt = 0; mt < 4; ++mt)
        acc[mt][nt] = __builtin_amdgcn_mfma_scale_f32_16x16x128_f8f6f4(
            afr[mt], bfr, acc[mt][nt], 0, 0,
            0, 0x7F7F7F7F, 0, 0x7F7F7F7F);
    }
  }

  // epilogue: z = acc/1024 + bias -> bf16
  const float SC = 1.0f / 1024.0f;
#pragma unroll
  for (int nt = 0; nt < 4; ++nt) {
    int n = n0 + wn * 64 + nt * 16 + l4;
    float bn = bias[n];
#pragma unroll
    for (int mt = 0; mt < 4; ++mt) {
      int ib = i0 + wm * 64 + mt * 16 + q * 4;
#pragma unroll
      for (int r = 0; r < 4; ++r)
        z[(size_t)(ib + r) * 512 + n] = f2bf(acc[mt][nt][r] * SC + bn);
    }
  }
}

// -------- norm: zn8 = fp8_e4m3( 16 * z_row / max(||z_row||,eps) ), z bf16 ----
__global__ __launch_bounds__(256) void norm_kernel(
    const unsigned short* __restrict__ z, unsigned char* __restrict__ zn8) {
  int row = blockIdx.x, t = threadIdx.x;
  ushort4 u = ((const ushort4*)z)[row * 256 + t];
  float a0 = bf2f(u.x), a1 = bf2f(u.y), a2 = bf2f(u.z), a3 = bf2f(u.w);
  float ss = a0 * a0 + a1 * a1 + a2 * a2 + a3 * a3;
#pragma unroll
  for (int off = 1; off < 64; off <<= 1) ss += __shfl_xor(ss, off);
  __shared__ float red[4];
  if ((t & 63) == 0) red[t >> 6] = ss;
  __syncthreads();
  float tot = red[0] + red[1] + red[2] + red[3];
  float inv = 16.f / fmaxf(sqrtf(tot), 1e-8f);
  int p = __builtin_amdgcn_cvt_pk_fp8_f32(a0 * inv, a1 * inv, 0, false);
  p = __builtin_amdgcn_cvt_pk_fp8_f32(a2 * inv, a3 * inv, p, true);
  ((int*)zn8)[row * 256 + t] = p;
}

// -------- GEMM2 fp8 symmetric: 256^2 tile, 8 waves, 4-phase/K-tile ----------
// Triangle of 256^2 blocks over 8192 rows: 32x32 -> 528 blocks, partitioned
// into 4x4-block supertiles (8 supertile-rows; diag supertile = 10 blocks,
// off-diag = 16). Working set per supertile: 1 MB A-rows + 1 MB B-rows
// <= 4 MB per-XCD L2. XCD chunking: g = (bid&7)*66 + bid>>3 (528 = 8*66).
// Per wave: 128x64 output, acc[8][4] f32x4. LDS 128 KB: A dbuf 2x32KB,
// B dbuf 2x32KB, XOR panel swizzle (panel = k-quarter, stride 8192).
// Schedule per K-tile (BK=128): issue ALL 8 next-tile panel stages at tile
// top, then 4 phases {ds_read subtile -> s_barrier -> setprio(1) 8 MFMA
// setprio(0) -> s_barrier}; single vmcnt(0) at tile end (~full tile of
// cover; with 2-deep buffering nothing is issued after it -> counted-wait
// equivalent, never a mid-pipeline drain).
// A-frag lane L: m=L&15, k=(L>>4)*32+j. C/D: col=L&15, row=(L>>4)*4+reg.
__global__ __launch_bounds__(512) void gemm2_kernel(
    const unsigned char* __restrict__ zn8,
    float* __restrict__ sumexp, float* __restrict__ pos) {
  __shared__ unsigned char smem[131072] __attribute__((aligned(16)));
  // --- supertile triangle decode with XCD chunking (bijection over 528) ---
  int g = (blockIdx.x & 7) * 66 + (blockIdx.x >> 3);
  int rem = g, SI = 0;
#pragma unroll 1
  for (; SI < 8; ++SI) {
    int rowcnt = 10 + (7 - SI) * 16;
    if (rem < rowcnt) break;
    rem -= rowcnt;
  }
  int bi, bj;
  if (rem < 10) {                       // diagonal supertile: 4x4 triangle
    int ti = 0;
    while (rem >= 4 - ti) { rem -= 4 - ti; ++ti; }
    bi = SI * 4 + ti;
    bj = bi + rem;
  } else {                              // off-diagonal supertile: 4x4 full
    rem -= 10;
    int SJ = SI + 1 + (rem >> 4);
    int l = rem & 15;
    bi = SI * 4 + (l >> 2);
    bj = SJ * 4 + (l & 3);
  }
  bool diag = (bi == bj);
  int i0 = bi * 256, j0 = bj * 256;

  int tid = threadIdx.x, L = tid & 63, w = tid >> 6;
  int wm = w >> 2, wn = w & 3;          // 2 x 4 wave grid
  int l4 = L & 15, q = L >> 4;
  int panel = q * 8192;

  int lp = L ^ ((L >> 3) & 7);
  int srow = w * 32 + (lp >> 1), sh = lp & 1;   // srow in [0,256)
  int ldst = (tid & ~63) * 16;                  // wave-uniform LDS base

  // precomputed swizzled slot byte-offsets (lo half; hi = ^16)
  int pA[8], pB[4];
#pragma unroll
  for (int mt = 0; mt < 8; ++mt) {
    int r = wm * 128 + mt * 16 + l4;
    pA[mt] = ((r * 2) ^ ((r >> 2) & 7)) * 16;
  }
#pragma unroll
  for (int nt = 0; nt < 4; ++nt) {
    int r = wn * 64 + nt * 16 + l4;
    pB[nt] = ((r * 2) ^ ((r >> 2) & 7)) * 16;
  }

  f32x4 acc[8][4];
#pragma unroll
  for (int a = 0; a < 8; ++a)
#pragma unroll
    for (int bq = 0; bq < 4; ++bq) acc[a][bq] = (f32x4)0.f;

  const unsigned char* Ag = zn8 + (size_t)(i0 + srow) * 1024 + sh * 16;
  const unsigned char* Bg = zn8 + (size_t)(j0 + srow) * 1024 + sh * 16;

  // stage one 8 KB panel (512 threads x 16 B) of A or B into buffer nc
  auto stA = [&](int nc, int kk, int t) {
    __builtin_amdgcn_global_load_lds(
        (const __attribute__((address_space(1))) void*)(Ag + kk + t * 32),
        (__attribute__((address_space(3))) void*)(smem + nc * 32768 + t * 8192 + ldst),
        16, 0, 0);
  };
  auto stB = [&](int nc, int kk, int t) {
    __builtin_amdgcn_global_load_lds(
        (const __attribute__((address_space(1))) void*)(Bg + kk + t * 32),
        (__attribute__((address_space(3))) void*)(smem + 65536 + nc * 32768 + t * 8192 + ldst),
        16, 0, 0);
  };

  // prologue: stage K-tile 0 into buf 0, drain, publish
  stA(0, 0, 0); stA(0, 0, 1); stA(0, 0, 2); stA(0, 0, 3);
  if (!diag) { stB(0, 0, 0); stB(0, 0, 1); stB(0, 0, 2); stB(0, 0, 3); }
  asm volatile("s_waitcnt vmcnt(0)" ::: "memory");
  __builtin_amdgcn_s_barrier();
  __builtin_amdgcn_sched_barrier(0);

#pragma unroll 1
  for (int t = 0; t < 8; ++t) {
    int c = t & 1, nc = c ^ 1;
    const unsigned char* Asb = smem + c * 32768;
    const unsigned char* Bsb = diag ? Asb : smem + 65536 + c * 32768;
    int k1 = t * 128 + 128;

    // ---- tile top: issue ALL next-tile stages (max cover for the
    // end-of-tile vmcnt(0)). Safe: each wave writes only its own LDS
    // stripe, and all reads of buf nc were register-consumed before the
    // barrier that ended tile t-1.
    if (t < 7) {
      stA(nc, k1, 0); stA(nc, k1, 1); stA(nc, k1, 2); stA(nc, k1, 3);
      if (!diag) { stB(nc, k1, 0); stB(nc, k1, 1); stB(nc, k1, 2); stB(nc, k1, 3); }
    }
    __builtin_amdgcn_sched_barrier(0);

    i32x8 afr[4], bf0[2], bf1[2];
    // ---- phase 0: A-half0 + B nt{0,1} reads ----
#pragma unroll
    for (int mt = 0; mt < 4; ++mt) {
      i32x4 lo = *(const i32x4*)(Asb + panel + pA[mt]);
      i32x4 hi = *(const i32x4*)(Asb + panel + (pA[mt] ^ 16));
      afr[mt] = (i32x8){lo.x, lo.y, lo.z, lo.w, hi.x, hi.y, hi.z, hi.w};
    }
#pragma unroll
    for (int nt = 0; nt < 2; ++nt) {
      i32x4 lo = *(const i32x4*)(Bsb + panel + pB[nt]);
      i32x4 hi = *(const i32x4*)(Bsb + panel + (pB[nt] ^ 16));
      bf0[nt] = (i32x8){lo.x, lo.y, lo.z, lo.w, hi.x, hi.y, hi.z, hi.w};
    }
    __builtin_amdgcn_s_barrier();
    __builtin_amdgcn_sched_barrier(0);
    __builtin_amdgcn_s_setprio(1);
#pragma unroll
    for (int mt = 0; mt < 4; ++mt)
#pragma unroll
      for (int nt = 0; nt < 2; ++nt)
        acc[mt][nt] = __builtin_amdgcn_mfma_scale_f32_16x16x128_f8f6f4(
            afr[mt], bf0[nt], acc[mt][nt], 0, 0, 0, 0x7F7F7F7F, 0, 0x7F7F7F7F);
    __builtin_amdgcn_s_setprio(0);
    __builtin_amdgcn_s_barrier();
    __builtin_amdgcn_sched_barrier(0);

    // ---- phase 1: B nt{2,3} reads ----
#pragma unroll
    for (int nt = 0; nt < 2; ++nt) {
      i32x4 lo = *(const i32x4*)(Bsb + panel + pB[2 + nt]);
      i32x4 hi = *(const i32x4*)(Bsb + panel + (pB[2 + nt] ^ 16));
      bf1[nt] = (i32x8){lo.x, lo.y, lo.z, lo.w, hi.x, hi.y, hi.z, hi.w};
    }
    __builtin_amdgcn_s_barrier();
    __builtin_amdgcn_sched_barrier(0);
    __builtin_amdgcn_s_setprio(1);
#pragma unroll
    for (int mt = 0; mt < 4; ++mt)
#pragma unroll
      for (int nt = 0; nt < 2; ++nt)
        acc[mt][2 + nt] = __builtin_amdgcn_mfma_scale_f32_16x16x128_f8f6f4(
            afr[mt], bf1[nt], acc[mt][2 + nt], 0, 0, 0, 0x7F7F7F7F, 0, 0x7F7F7F7F);
    __builtin_amdgcn_s_setprio(0);
    __builtin_amdgcn_s_barrier();
    __builtin_amdgcn_sched_barrier(0);

    // ---- phase 2: A-half1 reads ----
#pragma unroll
    for (int mt = 0; mt < 4; ++mt) {
      i32x4 lo = *(const i32x4*)(Asb + panel + pA[4 + mt]);
      i32x4 hi = *(const i32x4*)(Asb + panel + (pA[4 + mt] ^ 16));
      afr[mt] = (i32x8){lo.x, lo.y, lo.z, lo.w, hi.x, hi.y, hi.z, hi.w};
    }
    __builtin_amdgcn_s_barrier();
    __builtin_amdgcn_sched_barrier(0);
    __builtin_amdgcn_s_setprio(1);
#pragma unroll
    for (int mt = 0; mt < 4; ++mt)
#pragma unroll
      for (int nt = 0; nt < 2; ++nt)
        acc[4 + mt][2 + nt] = __builtin_amdgcn_mfma_scale_f32_16x16x128_f8f6f4(
            afr[mt], bf1[nt], acc[4 + mt][2 + nt], 0, 0, 0, 0x7F7F7F7F, 0, 0x7F7F7F7F);
    __builtin_amdgcn_s_setprio(0);
    __builtin_amdgcn_s_barrier();
    __builtin_amdgcn_sched_barrier(0);

    // ---- phase 3: MFMA on held bf0; end-of-tile drain + publish ----
    __builtin_amdgcn_s_setprio(1);
#pragma unroll
    for (int mt = 0; mt < 4; ++mt)
#pragma unroll
      for (int nt = 0; nt < 2; ++nt)
        acc[4 + mt][nt] = __builtin_amdgcn_mfma_scale_f32_16x16x128_f8f6f4(
            afr[mt], bf0[nt], acc[4 + mt][nt], 0, 0, 0, 0x7F7F7F7F, 0, 0x7F7F7F7F);
    __builtin_amdgcn_s_setprio(0);
    asm volatile("s_waitcnt vmcnt(0)" ::: "memory");
    __builtin_amdgcn_s_barrier();
    __builtin_amdgcn_sched_barrier(0);
  }

  // ---- epilogue: s = acc*10/256; diag mask; pos; exp; row/col sums ----
  const float SC = 10.0f / 256.0f;
  float rs[8][4];
  float cs[4] = {0.f, 0.f, 0.f, 0.f};
#pragma unroll
  for (int mt = 0; mt < 8; ++mt)
#pragma unroll
    for (int r = 0; r < 4; ++r) rs[mt][r] = 0.f;
  int ib = i0 + wm * 128 + q * 4;
  int jb = j0 + wn * 64 + l4;
#pragma unroll
  for (int mt = 0; mt < 8; ++mt)
#pragma unroll
    for (int nt = 0; nt < 4; ++nt) {
      int j = jb + nt * 16;
#pragma unroll
      for (int r = 0; r < 4; ++r) {
        int i = ib + mt * 16 + r;
        float s = acc[mt][nt][r] * SC;
        if (j == (i ^ 4096)) { pos[i] = s; pos[j] = s; }
        float e = (i == j) ? 0.f : __expf(s);
        rs[mt][r] += e;
        if (!diag) cs[nt] += e;
      }
    }
  // reduce row-sums across the 16 lanes of each q-group
#pragma unroll
  for (int mt = 0; mt < 8; ++mt)
#pragma unroll
    for (int r = 0; r < 4; ++r) {
      float v = rs[mt][r];
      v += __shfl_xor(v, 1); v += __shfl_xor(v, 2);
      v += __shfl_xor(v, 4); v += __shfl_xor(v, 8);
      rs[mt][r] = v;
    }
  // each lane commits two rows: sel = l4 (mt 0..3) and 16+l4 (mt 4..7)
  float v1 = rs[0][0], v2 = rs[4][0];
#pragma unroll
  for (int mt = 0; mt < 4; ++mt)
#pragma unroll
    for (int r = 0; r < 4; ++r) {
      if (l4 == mt * 4 + r) { v1 = rs[mt][r]; v2 = rs[4 + mt][r]; }
    }
  int rowi = ib + (l4 >> 2) * 16 + (l4 & 3);
  atomicAdd(&sumexp[rowi], v1);
  atomicAdd(&sumexp[rowi + 64], v2);
  if (!diag) {
#pragma unroll
    for (int nt = 0; nt < 4; ++nt) {
      float v = cs[nt];
      v += __shfl_xor(v, 16); v += __shfl_xor(v, 32);
      if (q == 0) atomicAdd(&sumexp[jb + nt * 16], v);
    }
  }
}

// -------- finalize: out += mean-partial(log(sumexp) - pos), 16 blocks --------
__global__ __launch_bounds__(512) void finalize_kernel(
    const float* __restrict__ sumexp, const float* __restrict__ pos,
    float* __restrict__ out) {
  int t = threadIdx.x;
  int i = blockIdx.x * 512 + t;
  float s = logf(sumexp[i]) - pos[i];
#pragma unroll
  for (int off = 1; off < 64; off <<= 1) s += __shfl_xor(s, off);
  __shared__ float red[8];
  if ((t & 63) == 0) red[t >> 6] = s;
  __syncthreads();
  if (t == 0) {
    float tot = 0.f;
    for (int k2 = 0; k2 < 8; ++k2) tot += red[k2];
    atomicAdd(out, tot * (1.0f / 8192.0f));
  }
}

extern "C" void kernel_launch(void* const* d_in, const int* in_sizes, int n_in,
                              void* d_out, int out_size, void* d_ws, size_t ws_size,
                              hipStream_t stream) {
  const float* x = (const float*)d_in[0];
  const float* w = (const float*)d_in[1];
  const float* b = (const float*)d_in[2];
  float* out = (float*)d_out;
  char* ws = (char*)d_ws;
  unsigned char* wt8 = (unsigned char*)(ws);
  unsigned char* x8  = (unsigned char*)(ws + 1048576);
  unsigned short* z  = (unsigned short*)(ws + 17825792);
  unsigned char* zn8 = (unsigned char*)(ws + 68157440);
  float* sumexp      = (float*)(ws + 84934656);
  float* pos         = (float*)(ws + 84967424);

  prep2_kernel<<<16384, 256, 0, stream>>>(x, w, x8, wt8, sumexp, out);
  gemm1q_kernel<<<512, 256, 0, stream>>>(x8, wt8, b, z);
  norm_kernel<<<8192, 256, 0, stream>>>(z, zn8);
  gemm2_kernel<<<528, 512, 0, stream>>>(zn8, sumexp, pos);
  finalize_kernel<<<16, 512, 0, stream>>>(sumexp, pos, out);
}

// Round 4
// 183.331 us; speedup vs baseline: 1.0690x; 1.0690x over previous
//
#include <hip/hip_runtime.h>
#include <hip/hip_bf16.h>
#include <stdint.h>

// Problem: B=8192, E=1024, P=512. x:[8192,2048] f32, w:[1024,512] f32, b:[512] f32.
// out: scalar = mean_i( -S[i,i^4096]/T + log(sum_{j!=i} exp(S[i,j]/T)) ),
// S = zn zn^T (symmetric -> upper triangle of 128x128 blocks), T=0.1.
// Pipeline: prep2 -> gemm1q (fp8 MX, R0) -> norm -> gemm2 (fp8 MX, R0
// supertile triangle, NOW 2 waves x 128x64 tiles) -> finalize.
//
// R4: abandon 8-phase branch (R2/R3 regressed: 1 block/CU + grid-528 tail +
// phase lockstep). Back to R0 skeleton. gemm2 change: 128-thread blocks,
// 2 waves of 128x64 output (acc[8][4]) -> fragment reads 64->48 KB per
// K-step (LDS-bound resource -17%), 32 KB LDS + ~200 regs -> 4 blocks/CU
// co-resident (was 3) for cross-block stage-latency hiding.
//
// ws layout (bytes):
//   wt8 fp8  [512][1024]    @ 0
//   x8  fp8  [16384][1024]  @ 1048576
//   z   bf16 [16384][512]   @ 17825792
//   zn8 fp8  [8192][1024]   @ 68157440
//   sumexp f32[8192]        @ 84934656
//   pos    f32[8192]        @ 84967424

typedef __attribute__((ext_vector_type(4))) float f32x4;
typedef __attribute__((ext_vector_type(4))) int i32x4;
typedef __attribute__((ext_vector_type(8))) int i32x8;

__device__ __forceinline__ unsigned short f2bf(float f) {
  union { float f; unsigned int u; } v; v.f = f;
  unsigned int u = v.u;
  u += 0x7FFFu + ((u >> 16) & 1u);
  return (unsigned short)(u >> 16);
}

__device__ __forceinline__ float bf2f(unsigned short s) {
  return __uint_as_float(((unsigned int)s) << 16);
}

// ---------------- prep2: x8 = fp8(16*relu(x)); wt8 = fp8(64*w^T); zeros ------
__global__ __launch_bounds__(256) void prep2_kernel(
    const float* __restrict__ x, const float* __restrict__ w,
    unsigned char* __restrict__ x8, unsigned char* __restrict__ wt8,
    float* __restrict__ sumexp, float* __restrict__ out) {
  int tid = blockIdx.x * 256 + threadIdx.x;
  float4 v = ((const float4*)x)[tid];
  int p = __builtin_amdgcn_cvt_pk_fp8_f32(fmaxf(v.x, 0.f) * 16.f,
                                          fmaxf(v.y, 0.f) * 16.f, 0, false);
  p = __builtin_amdgcn_cvt_pk_fp8_f32(fmaxf(v.z, 0.f) * 16.f,
                                      fmaxf(v.w, 0.f) * 16.f, p, true);
  ((int*)x8)[tid] = p;
  if (tid < 512 * 1024) {
    int k = tid & 1023, n = tid >> 10;
    int q = __builtin_amdgcn_cvt_pk_fp8_f32(w[k * 512 + n] * 64.f, 0.f, 0, false);
    wt8[(n << 10) + k] = (unsigned char)(q & 0xFF);
  }
  if (tid < 8192) sumexp[tid] = 0.f;
  if (tid == 0) out[0] = 0.f;
}

// -------- gemm1q: z[16384,512](bf16) = relu(x)@w + b via fp8 MX --------------
// R0-proven: 128x128 tile, BK=128, XOR-swizzled 16 KB LDS/matrix, 2-barrier.
__global__ __launch_bounds__(256) void gemm1q_kernel(
    const unsigned char* __restrict__ x8, const unsigned char* __restrict__ wt8,
    const float* __restrict__ bias, unsigned short* __restrict__ z) {
  __shared__ unsigned char As[16384] __attribute__((aligned(16)));
  __shared__ unsigned char Bs[16384] __attribute__((aligned(16)));
  int b = blockIdx.x;
  int kk = b >> 3;
  int i0 = ((b & 7) * 16 + (kk >> 2)) * 128;
  int n0 = (kk & 3) * 128;

  int tid = threadIdx.x, L = tid & 63, w = tid >> 6;
  int wm = w >> 1, wn = w & 1;
  int l4 = L & 15, q = L >> 4;
  int panel = q * 4096;

  int lp = L ^ ((L >> 3) & 7);
  int srow = w * 32 + (lp >> 1), sh = lp & 1;

  f32x4 acc[4][4];
#pragma unroll
  for (int a = 0; a < 4; ++a)
#pragma unroll
    for (int bq = 0; bq < 4; ++bq) acc[a][bq] = (f32x4)0.f;

  const unsigned char* Ag = x8 + (size_t)(i0 + srow) * 1024 + sh * 16;
  const unsigned char* Bg = wt8 + (size_t)(n0 + srow) * 1024 + sh * 16;

#pragma unroll 1
  for (int k0 = 0; k0 < 1024; k0 += 128) {
    __syncthreads();
#pragma unroll
    for (int t = 0; t < 4; ++t)
      __builtin_amdgcn_global_load_lds(
          (const __attribute__((address_space(1))) void*)(Ag + k0 + t * 32),
          (__attribute__((address_space(3))) void*)(As + t * 4096 + (tid & ~63) * 16),
          16, 0, 0);
#pragma unroll
    for (int t = 0; t < 4; ++t)
      __builtin_amdgcn_global_load_lds(
          (const __attribute__((address_space(1))) void*)(Bg + k0 + t * 32),
          (__attribute__((address_space(3))) void*)(Bs + t * 4096 + (tid & ~63) * 16),
          16, 0, 0);
    __syncthreads();
    i32x8 afr[4];
#pragma unroll
    for (int mt = 0; mt < 4; ++mt) {
      int row = wm * 64 + mt * 16 + l4;
      int p0 = (row * 2) ^ ((row >> 2) & 7);
      i32x4 lo = *(const i32x4*)(As + panel + p0 * 16);
      i32x4 hi = *(const i32x4*)(As + panel + (p0 ^ 1) * 16);
      afr[mt] = (i32x8){lo.x, lo.y, lo.z, lo.w, hi.x, hi.y, hi.z, hi.w};
    }
#pragma unroll
    for (int nt = 0; nt < 4; ++nt) {
      int row = wn * 64 + nt * 16 + l4;
      int p0 = (row * 2) ^ ((row >> 2) & 7);
      i32x4 lo = *(const i32x4*)(Bs + panel + p0 * 16);
      i32x4 hi = *(const i32x4*)(Bs + panel + (p0 ^ 1) * 16);
      i32x8 bfr = (i32x8){lo.x, lo.y, lo.z, lo.w, hi.x, hi.y, hi.z, hi.w};
#pragma unroll
      for (int mt = 0; mt < 4; ++mt)
        acc[mt][nt] = __builtin_amdgcn_mfma_scale_f32_16x16x128_f8f6f4(
            afr[mt], bfr, acc[mt][nt], 0, 0,
            0, 0x7F7F7F7F, 0, 0x7F7F7F7F);
    }
  }

  // epilogue: z = acc/1024 + bias -> bf16
  const float SC = 1.0f / 1024.0f;
#pragma unroll
  for (int nt = 0; nt < 4; ++nt) {
    int n = n0 + wn * 64 + nt * 16 + l4;
    float bn = bias[n];
#pragma unroll
    for (int mt = 0; mt < 4; ++mt) {
      int ib = i0 + wm * 64 + mt * 16 + q * 4;
#pragma unroll
      for (int r = 0; r < 4; ++r)
        z[(size_t)(ib + r) * 512 + n] = f2bf(acc[mt][nt][r] * SC + bn);
    }
  }
}

// -------- norm: zn8 = fp8_e4m3( 16 * z_row / max(||z_row||,eps) ), z bf16 ----
__global__ __launch_bounds__(256) void norm_kernel(
    const unsigned short* __restrict__ z, unsigned char* __restrict__ zn8) {
  int row = blockIdx.x, t = threadIdx.x;
  ushort4 u = ((const ushort4*)z)[row * 256 + t];
  float a0 = bf2f(u.x), a1 = bf2f(u.y), a2 = bf2f(u.z), a3 = bf2f(u.w);
  float ss = a0 * a0 + a1 * a1 + a2 * a2 + a3 * a3;
#pragma unroll
  for (int off = 1; off < 64; off <<= 1) ss += __shfl_xor(ss, off);
  __shared__ float red[4];
  if ((t & 63) == 0) red[t >> 6] = ss;
  __syncthreads();
  float tot = red[0] + red[1] + red[2] + red[3];
  float inv = 16.f / fmaxf(sqrtf(tot), 1e-8f);
  int p = __builtin_amdgcn_cvt_pk_fp8_f32(a0 * inv, a1 * inv, 0, false);
  p = __builtin_amdgcn_cvt_pk_fp8_f32(a2 * inv, a3 * inv, p, true);
  ((int*)zn8)[row * 256 + t] = p;
}

// -------- GEMM2 fp8 symmetric: 128^2 block, 2 waves x 128x64, BK=128 ---------
// R0's supertile-XCD swizzled triangle (2080 blocks) + R0 2-barrier K-loop.
// Each wave owns the FULL 128 rows x its 64-col half: acc[8][4] f32x4.
// Fragment reads/K-step: A 16 KB/wave + B 8 KB/wave (was 16 KB/wave at
// 64x64) -> block LDS traffic 96->80 KB. 32 KB LDS, ~200 regs -> 4 blocks/CU.
// Staging (128 thr): sub-step hb: slot s = hb*128+tid; e = tid^((tid>>3)&7);
// row = hb*64+(e>>1), half = e&1  (inverse of read swizzle
// p0 = (row*2)^((row>>2)&7), verified algebraically vs R0 involution).
// A-frag lane L: m=L&15, k=(L>>4)*32+j. C/D: col=L&15, row=(L>>4)*4+reg.
__global__ __launch_bounds__(128, 2) void gemm2_kernel(
    const unsigned char* __restrict__ zn8,
    float* __restrict__ sumexp, float* __restrict__ pos) {
  __shared__ unsigned char As[16384] __attribute__((aligned(16)));
  __shared__ unsigned char Bs[16384] __attribute__((aligned(16)));
  // --- supertile decode (R0-proven bijection over the 2080 triangle blocks) ---
  int g = (blockIdx.x & 7) * 260 + (blockIdx.x >> 3);
  int SI = 0, rem = g;
#pragma unroll 1
  for (SI = 0; SI < 8; ++SI) {
    int rowcnt = 36 + (7 - SI) * 64;
    if (rem < rowcnt) break;
    rem -= rowcnt;
  }
  int bi, bj;
  if (rem < 36) {                       // diagonal supertile (8x8 triangle)
    int ti = 0;
    while (rem >= 8 - ti) { rem -= 8 - ti; ++ti; }
    bi = SI * 8 + ti;
    bj = bi + rem;
  } else {                              // off-diagonal supertile
    rem -= 36;
    int SJ = SI + 1 + (rem >> 6);
    int l = rem & 63;
    bi = SI * 8 + (l >> 3);
    bj = SJ * 8 + (l & 7);
  }
  bool diag = (bi == bj);
  int i0 = bi * 128, j0 = bj * 128;

  int tid = threadIdx.x, L = tid & 63, w = tid >> 6;   // w in {0,1}
  int l4 = L & 15, q = L >> 4;
  int panel = q * 4096;
  int lw = w * 1024;                    // wave-uniform LDS sub-step base

  // staging content map (derived inverse; see header comment)
  int e = tid ^ ((tid >> 3) & 7);
  int r2 = e >> 1, hh = e & 1;

  // read-side swizzled slot byte-offsets (lo half; hi = ^16)
  int pA[8], pB[4];
#pragma unroll
  for (int mt = 0; mt < 8; ++mt) {
    int r = mt * 16 + l4;
    pA[mt] = ((r * 2) ^ ((r >> 2) & 7)) * 16;
  }
#pragma unroll
  for (int nt = 0; nt < 4; ++nt) {
    int r = w * 64 + nt * 16 + l4;
    pB[nt] = ((r * 2) ^ ((r >> 2) & 7)) * 16;
  }

  f32x4 acc[8][4];
#pragma unroll
  for (int a = 0; a < 8; ++a)
#pragma unroll
    for (int bq = 0; bq < 4; ++bq) acc[a][bq] = (f32x4)0.f;

  const unsigned char* Ag0 = zn8 + (size_t)(i0 + r2) * 1024 + hh * 16;
  const unsigned char* Ag1 = zn8 + (size_t)(i0 + 64 + r2) * 1024 + hh * 16;
  const unsigned char* Bg0 = zn8 + (size_t)(j0 + r2) * 1024 + hh * 16;
  const unsigned char* Bg1 = zn8 + (size_t)(j0 + 64 + r2) * 1024 + hh * 16;
  const unsigned char* Bsrc = diag ? (const unsigned char*)As : (const unsigned char*)Bs;

#pragma unroll 1
  for (int k0 = 0; k0 < 1024; k0 += 128) {
    __syncthreads();
#pragma unroll
    for (int p = 0; p < 4; ++p) {
      __builtin_amdgcn_global_load_lds(
          (const __attribute__((address_space(1))) void*)(Ag0 + k0 + p * 32),
          (__attribute__((address_space(3))) void*)(As + p * 4096 + lw),
          16, 0, 0);
      __builtin_amdgcn_global_load_lds(
          (const __attribute__((address_space(1))) void*)(Ag1 + k0 + p * 32),
          (__attribute__((address_space(3))) void*)(As + p * 4096 + 2048 + lw),
          16, 0, 0);
    }
    if (!diag) {
#pragma unroll
      for (int p = 0; p < 4; ++p) {
        __builtin_amdgcn_global_load_lds(
            (const __attribute__((address_space(1))) void*)(Bg0 + k0 + p * 32),
            (__attribute__((address_space(3))) void*)(Bs + p * 4096 + lw),
            16, 0, 0);
        __builtin_amdgcn_global_load_lds(
            (const __attribute__((address_space(1))) void*)(Bg1 + k0 + p * 32),
            (__attribute__((address_space(3))) void*)(Bs + p * 4096 + 2048 + lw),
            16, 0, 0);
      }
    }
    __syncthreads();
    i32x8 bfr[4];
#pragma unroll
    for (int nt = 0; nt < 4; ++nt) {
      i32x4 lo = *(const i32x4*)(Bsrc + panel + pB[nt]);
      i32x4 hi = *(const i32x4*)(Bsrc + panel + (pB[nt] ^ 16));
      bfr[nt] = (i32x8){lo.x, lo.y, lo.z, lo.w, hi.x, hi.y, hi.z, hi.w};
    }
#pragma unroll
    for (int mt = 0; mt < 8; ++mt) {
      i32x4 lo = *(const i32x4*)(As + panel + pA[mt]);
      i32x4 hi = *(const i32x4*)(As + panel + (pA[mt] ^ 16));
      i32x8 afr = (i32x8){lo.x, lo.y, lo.z, lo.w, hi.x, hi.y, hi.z, hi.w};
#pragma unroll
      for (int nt = 0; nt < 4; ++nt)
        acc[mt][nt] = __builtin_amdgcn_mfma_scale_f32_16x16x128_f8f6f4(
            afr, bfr[nt], acc[mt][nt], 0, 0,
            0, 0x7F7F7F7F, 0, 0x7F7F7F7F);
    }
  }

  // ---- epilogue: s = acc*10/256; diag mask; pos; exp; row/col sums ----
  const float SC = 10.0f / 256.0f;
  float rs[8][4];
  float cs[4] = {0.f, 0.f, 0.f, 0.f};
#pragma unroll
  for (int mt = 0; mt < 8; ++mt)
#pragma unroll
    for (int r = 0; r < 4; ++r) rs[mt][r] = 0.f;
  int ib = i0 + q * 4;
  int jb = j0 + w * 64 + l4;
#pragma unroll
  for (int mt = 0; mt < 8; ++mt)
#pragma unroll
    for (int nt = 0; nt < 4; ++nt) {
      int j = jb + nt * 16;
#pragma unroll
      for (int r = 0; r < 4; ++r) {
        int i = ib + mt * 16 + r;
        float s = acc[mt][nt][r] * SC;
        if (j == (i ^ 4096)) { pos[i] = s; pos[j] = s; }
        float e2 = (i == j) ? 0.f : __expf(s);
        rs[mt][r] += e2;
        if (!diag) cs[nt] += e2;
      }
    }
  // reduce row-sums across the 16 lanes of each q-group
#pragma unroll
  for (int mt = 0; mt < 8; ++mt)
#pragma unroll
    for (int r = 0; r < 4; ++r) {
      float v = rs[mt][r];
      v += __shfl_xor(v, 1); v += __shfl_xor(v, 2);
      v += __shfl_xor(v, 4); v += __shfl_xor(v, 8);
      rs[mt][r] = v;
    }
  // each lane commits two rows: mt = l4>>2 (rows 0-63) and +4 (rows 64-127)
  float v1 = rs[0][0], v2 = rs[4][0];
#pragma unroll
  for (int mt = 0; mt < 4; ++mt)
#pragma unroll
    for (int r = 0; r < 4; ++r) {
      if (l4 == mt * 4 + r) { v1 = rs[mt][r]; v2 = rs[4 + mt][r]; }
    }
  int rowi = ib + (l4 >> 2) * 16 + (l4 & 3);
  atomicAdd(&sumexp[rowi], v1);
  atomicAdd(&sumexp[rowi + 64], v2);
  if (!diag) {
#pragma unroll
    for (int nt = 0; nt < 4; ++nt) {
      float v = cs[nt];
      v += __shfl_xor(v, 16); v += __shfl_xor(v, 32);
      if (q == 0) atomicAdd(&sumexp[jb + nt * 16], v);
    }
  }
}

// -------- finalize: out += mean-partial(log(sumexp) - pos), 16 blocks --------
__global__ __launch_bounds__(512) void finalize_kernel(
    const float* __restrict__ sumexp, const float* __restrict__ pos,
    float* __restrict__ out) {
  int t = threadIdx.x;
  int i = blockIdx.x * 512 + t;
  float s = logf(sumexp[i]) - pos[i];
#pragma unroll
  for (int off = 1; off < 64; off <<= 1) s += __shfl_xor(s, off);
  __shared__ float red[8];
  if ((t & 63) == 0) red[t >> 6] = s;
  __syncthreads();
  if (t == 0) {
    float tot = 0.f;
    for (int k2 = 0; k2 < 8; ++k2) tot += red[k2];
    atomicAdd(out, tot * (1.0f / 8192.0f));
  }
}

extern "C" void kernel_launch(void* const* d_in, const int* in_sizes, int n_in,
                              void* d_out, int out_size, void* d_ws, size_t ws_size,
                              hipStream_t stream) {
  const float* x = (const float*)d_in[0];
  const float* w = (const float*)d_in[1];
  const float* b = (const float*)d_in[2];
  float* out = (float*)d_out;
  char* ws = (char*)d_ws;
  unsigned char* wt8 = (unsigned char*)(ws);
  unsigned char* x8  = (unsigned char*)(ws + 1048576);
  unsigned short* z  = (unsigned short*)(ws + 17825792);
  unsigned char* zn8 = (unsigned char*)(ws + 68157440);
  float* sumexp      = (float*)(ws + 84934656);
  float* pos         = (float*)(ws + 84967424);

  prep2_kernel<<<16384, 256, 0, stream>>>(x, w, x8, wt8, sumexp, out);
  gemm1q_kernel<<<512, 256, 0, stream>>>(x8, wt8, b, z);
  norm_kernel<<<8192, 256, 0, stream>>>(z, zn8);
  gemm2_kernel<<<2080, 128, 0, stream>>>(zn8, sumexp, pos);
  finalize_kernel<<<16, 512, 0, stream>>>(sumexp, pos, out);
}

// Round 6
// 175.795 us; speedup vs baseline: 1.1148x; 1.0429x over previous
//
#include <hip/hip_runtime.h>
#include <hip/hip_bf16.h>
#include <stdint.h>

// Problem: B=8192, E=1024, P=512. x:[8192,2048] f32, w:[1024,512] f32, b:[512] f32.
// out: scalar = mean_i( -S[i,i^4096]/T + log(sum_{j!=i} exp(S[i,j]/T)) ),
// S = zn zn^T (symmetric -> upper triangle of 128x128 blocks), T=0.1.
//
// R6 == R5 resubmission (container infra failure, no kernel verdict).
// Pipeline: prep2 (x8 only) + wtr (LDS-transpose w->wt8, coalesced) ->
// gemm1qn (FUSED proj+norm: 256 blocks x 512thr, 64 rows x 512 cols, BK=128
// dbuf, computes z in f32 regs, block-local row norms, writes zn8 directly;
// kills the z bf16 round-trip + norm kernel) -> gemm2 (EXACT R0: proven
// 61.5us) -> finalize.
//
// ws layout (bytes):
//   wt8 fp8  [512][1024]    @ 0
//   x8  fp8  [16384][1024]  @ 1048576
//   (z slot unused now)     @ 17825792
//   zn8 fp8  [8192][1024]   @ 68157440
//   sumexp f32[8192]        @ 84934656
//   pos    f32[8192]        @ 84967424

typedef __attribute__((ext_vector_type(4))) float f32x4;
typedef __attribute__((ext_vector_type(4))) int i32x4;
typedef __attribute__((ext_vector_type(8))) int i32x8;

__device__ __forceinline__ unsigned char f2fp8(float f) {
  int q = __builtin_amdgcn_cvt_pk_fp8_f32(f, 0.f, 0, false);
  return (unsigned char)(q & 0xFF);
}

// ---------------- prep2: x8 = fp8(16*relu(x)); zeros ------------------------
__global__ __launch_bounds__(256) void prep2_kernel(
    const float* __restrict__ x, unsigned char* __restrict__ x8,
    float* __restrict__ sumexp, float* __restrict__ out) {
  int tid = blockIdx.x * 256 + threadIdx.x;
  float4 v = ((const float4*)x)[tid];
  int p = __builtin_amdgcn_cvt_pk_fp8_f32(fmaxf(v.x, 0.f) * 16.f,
                                          fmaxf(v.y, 0.f) * 16.f, 0, false);
  p = __builtin_amdgcn_cvt_pk_fp8_f32(fmaxf(v.z, 0.f) * 16.f,
                                      fmaxf(v.w, 0.f) * 16.f, p, true);
  ((int*)x8)[tid] = p;
  if (tid < 8192) sumexp[tid] = 0.f;
  if (tid == 0) out[0] = 0.f;
}

// ---------------- wtr: wt8[n][k] = fp8(64*w[k][n]) via LDS transpose --------
// 64x64 tiles: grid 128 = 16 ktiles x 8 ntiles, 256 threads.
// Read coalesced (float4 rows of w), quantize, transpose in LDS, write
// 16B-coalesced rows of wt8. Replaces prep2's stride-2KB w reads.
__global__ __launch_bounds__(256) void wtr_kernel(
    const float* __restrict__ w, unsigned char* __restrict__ wt8) {
  __shared__ unsigned char lt[64][68];
  int b = blockIdx.x, t = threadIdx.x;
  int k0 = (b >> 3) * 64, n0 = (b & 7) * 64;
  int r = t >> 4, c = t & 15;
#pragma unroll
  for (int i = 0; i < 4; ++i) {
    int kl = i * 16 + r;
    float4 v = *(const float4*)&w[(size_t)(k0 + kl) * 512 + n0 + c * 4];
    int q = __builtin_amdgcn_cvt_pk_fp8_f32(v.x * 64.f, v.y * 64.f, 0, false);
    q = __builtin_amdgcn_cvt_pk_fp8_f32(v.z * 64.f, v.w * 64.f, q, true);
    *(int*)&lt[kl][c * 4] = q;
  }
  __syncthreads();
  int nl = t >> 2, ks = t & 3;
  union { unsigned char b8[16]; i32x4 v4; } u;
#pragma unroll
  for (int j = 0; j < 16; ++j) u.b8[j] = lt[ks * 16 + j][nl];
  *(i32x4*)&wt8[(size_t)(n0 + nl) * 1024 + k0 + ks * 16] = u.v4;
}

// -------- gemm1qn: zn8 = fp8(16*normrow(relu(x)@w + b)), fused ---------------
// 256 blocks x 512 thr (8 waves). Block = 64 x8-rows x 512 n-cols = 32 full
// zn rows. BK=128, dbuf LDS: A 2x8KB @0, B 2x64KB @16384 (144 KB total).
// Stage slot involution (R4-verified, row-count generic):
//   slot s -> e = s^((s>>3)&7), row = e>>1, half = e&1;
//   read p0 = (row*2)^((row>>2)&7) is its inverse.
// Wave w: cols [64w, 64w+64), all 64 rows; acc[4][4] f32x4 (R0 fragment code,
// wm=0, wn=w). Epilogue: z=acc/1024+bias (f32), ss butterfly over l4,
// cross-wave LDS reduce, inv = 16/max(||zn row||,1e-8), fp8 byte stores.
// A-frag lane L: m=L&15, k=(L>>4)*32+j. C/D: col=L&15, row=(L>>4)*4+reg.
__global__ __launch_bounds__(512, 2) void gemm1qn_kernel(
    const unsigned char* __restrict__ x8, const unsigned char* __restrict__ wt8,
    const float* __restrict__ bias, unsigned char* __restrict__ zn8) {
  __shared__ unsigned char smem[147456] __attribute__((aligned(16)));
  int i0 = blockIdx.x * 64;
  int tid = threadIdx.x, L = tid & 63, w = tid >> 6;
  int l4 = L & 15, q = L >> 4;

  // ---- staging decode ----
  // A: one slot per thread: panel pA=t>>7, slot sA=t&127
  int sA = tid & 127, pA = tid >> 7;
  int eA = sA ^ ((sA >> 3) & 7);
  int rA = eA >> 1, hA = eA & 1;
  const unsigned char* srcA = x8 + (size_t)(i0 + rA) * 1024 + pA * 32 + hA * 16;
  // B: per panel p, slots t and 512+t: e2 = 512+e1 -> rows r1 and r1+256
  int e1 = tid ^ ((tid >> 3) & 7);
  int rB = e1 >> 1, hB = e1 & 1;
  const unsigned char* srcB1 = wt8 + (size_t)rB * 1024 + hB * 16;
  const unsigned char* srcB2 = wt8 + (size_t)(rB + 256) * 1024 + hB * 16;

  auto stage = [&](int buf, int k0) {
    __builtin_amdgcn_global_load_lds(
        (const __attribute__((address_space(1))) void*)(srcA + k0),
        (__attribute__((address_space(3))) void*)(smem + buf * 8192 + tid * 16),
        16, 0, 0);
#pragma unroll
    for (int p = 0; p < 4; ++p) {
      __builtin_amdgcn_global_load_lds(
          (const __attribute__((address_space(1))) void*)(srcB1 + k0 + p * 32),
          (__attribute__((address_space(3))) void*)(smem + 16384 + buf * 65536 + p * 16384 + tid * 16),
          16, 0, 0);
      __builtin_amdgcn_global_load_lds(
          (const __attribute__((address_space(1))) void*)(srcB2 + k0 + p * 32),
          (__attribute__((address_space(3))) void*)(smem + 16384 + buf * 65536 + p * 16384 + 8192 + tid * 16),
          16, 0, 0);
    }
  };

  // ---- read-side swizzled offsets ----
  int pAo[4], pBo[4];
#pragma unroll
  for (int mt = 0; mt < 4; ++mt) {
    int r = mt * 16 + l4;
    pAo[mt] = ((r * 2) ^ ((r >> 2) & 7)) * 16;
  }
#pragma unroll
  for (int nt = 0; nt < 4; ++nt) {
    int r = w * 64 + nt * 16 + l4;
    pBo[nt] = ((r * 2) ^ ((r >> 2) & 7)) * 16;
  }

  f32x4 acc[4][4];
#pragma unroll
  for (int a = 0; a < 4; ++a)
#pragma unroll
    for (int bq = 0; bq < 4; ++bq) acc[a][bq] = (f32x4)0.f;

  stage(0, 0);
  __syncthreads();
#pragma unroll 1
  for (int s = 0; s < 8; ++s) {
    if (s < 7) stage((s + 1) & 1, (s + 1) * 128);
    const unsigned char* Ab = smem + (s & 1) * 8192 + q * 2048;
    const unsigned char* Bb = smem + 16384 + (s & 1) * 65536 + q * 16384;
    i32x8 afr[4];
#pragma unroll
    for (int mt = 0; mt < 4; ++mt) {
      i32x4 lo = *(const i32x4*)(Ab + pAo[mt]);
      i32x4 hi = *(const i32x4*)(Ab + (pAo[mt] ^ 16));
      afr[mt] = (i32x8){lo.x, lo.y, lo.z, lo.w, hi.x, hi.y, hi.z, hi.w};
    }
#pragma unroll
    for (int nt = 0; nt < 4; ++nt) {
      i32x4 lo = *(const i32x4*)(Bb + pBo[nt]);
      i32x4 hi = *(const i32x4*)(Bb + (pBo[nt] ^ 16));
      i32x8 bfr = (i32x8){lo.x, lo.y, lo.z, lo.w, hi.x, hi.y, hi.z, hi.w};
#pragma unroll
      for (int mt = 0; mt < 4; ++mt)
        acc[mt][nt] = __builtin_amdgcn_mfma_scale_f32_16x16x128_f8f6f4(
            afr[mt], bfr, acc[mt][nt], 0, 0,
            0, 0x7F7F7F7F, 0, 0x7F7F7F7F);
    }
    __syncthreads();
  }

  // ---- epilogue: z = acc/1024 + bias; row sumsq; norm; zn8 ----
  const float SC = 1.0f / 1024.0f;
  float bn[4];
#pragma unroll
  for (int nt = 0; nt < 4; ++nt) bn[nt] = bias[w * 64 + nt * 16 + l4];
  float ssp[4][4];
#pragma unroll
  for (int mt = 0; mt < 4; ++mt)
#pragma unroll
    for (int r = 0; r < 4; ++r) ssp[mt][r] = 0.f;
#pragma unroll
  for (int mt = 0; mt < 4; ++mt)
#pragma unroll
    for (int nt = 0; nt < 4; ++nt)
#pragma unroll
      for (int r = 0; r < 4; ++r) {
        float zv = acc[mt][nt][r] * SC + bn[nt];
        acc[mt][nt][r] = zv;
        ssp[mt][r] += zv * zv;
      }
  // butterfly over l4 (sums this wave's 64 cols per row)
#pragma unroll
  for (int mt = 0; mt < 4; ++mt)
#pragma unroll
    for (int r = 0; r < 4; ++r) {
      float v = ssp[mt][r];
      v += __shfl_xor(v, 1); v += __shfl_xor(v, 2);
      v += __shfl_xor(v, 4); v += __shfl_xor(v, 8);
      ssp[mt][r] = v;
    }
  float* ssbuf = (float*)smem;          // [64 rows][8 waves], aliases A (safe: post-barrier)
  if (l4 == 0) {
#pragma unroll
    for (int mt = 0; mt < 4; ++mt)
#pragma unroll
      for (int r = 0; r < 4; ++r)
        ssbuf[(mt * 16 + q * 4 + r) * 8 + w] = ssp[mt][r];
  }
  __syncthreads();
  float* invbuf = (float*)(smem + 2048);  // [32 zn rows]
  if (tid < 32) {
    float tot = 0.f;
#pragma unroll
    for (int j = 0; j < 8; ++j)
      tot += ssbuf[(2 * tid) * 8 + j] + ssbuf[(2 * tid + 1) * 8 + j];
    invbuf[tid] = 16.f / fmaxf(sqrtf(tot), 1e-8f);
  }
  __syncthreads();
#pragma unroll
  for (int mt = 0; mt < 4; ++mt)
#pragma unroll
    for (int r = 0; r < 4; ++r) {
      int zr = mt * 16 + q * 4 + r;
      float inv = invbuf[zr >> 1];
      int zg = i0 + zr;
      size_t base = (size_t)(zg >> 1) * 1024 + (zg & 1) * 512 + w * 64 + l4;
#pragma unroll
      for (int nt = 0; nt < 4; ++nt)
        zn8[base + nt * 16] = f2fp8(acc[mt][nt][r] * inv);
    }
}

// -------- GEMM2 fp8 symmetric: 16x16x128 MX, BK=128 (EXACT R0) ---------------
// Supertile-XCD swizzle: 64x64 block-triangle partitioned into 8x8 supertiles
// of 8x8 blocks (A+B working set ~2 MB <= 4 MB per-XCD L2). Permutation
// g = (b&7)*260 + (b>>3) gives each XCD a contiguous supertile-ordered range.
// A-frag lane L: m=L&15, k=(L>>4)*32+j. C/D: col=L&15, row=(L>>4)*4+reg.
__global__ __launch_bounds__(256, 3) void gemm2_kernel(
    const unsigned char* __restrict__ zn8,
    float* __restrict__ sumexp, float* __restrict__ pos) {
  __shared__ unsigned char As[16384] __attribute__((aligned(16)));
  __shared__ unsigned char Bs[16384] __attribute__((aligned(16)));
  // --- supertile decode (pure bijection over the 2080 triangle blocks) ---
  int g = (blockIdx.x & 7) * 260 + (blockIdx.x >> 3);
  int SI = 0, rem = g;
#pragma unroll 1
  for (SI = 0; SI < 8; ++SI) {
    int rowcnt = 36 + (7 - SI) * 64;
    if (rem < rowcnt) break;
    rem -= rowcnt;
  }
  int bi, bj;
  if (rem < 36) {                       // diagonal supertile (8x8 triangle)
    int ti = 0;
    while (rem >= 8 - ti) { rem -= 8 - ti; ++ti; }
    bi = SI * 8 + ti;
    bj = bi + rem;
  } else {                              // off-diagonal supertile
    rem -= 36;
    int SJ = SI + 1 + (rem >> 6);
    int l = rem & 63;
    bi = SI * 8 + (l >> 3);
    bj = SJ * 8 + (l & 7);
  }
  bool diag = (bi == bj);
  int i0 = bi * 128, j0 = bj * 128;

  int tid = threadIdx.x, L = tid & 63, w = tid >> 6;
  int wm = w >> 1, wn = w & 1;
  int l4 = L & 15;
  int panel = (L >> 4) * 4096;

  int lp = L ^ ((L >> 3) & 7);
  int srow = w * 32 + (lp >> 1), sh = lp & 1;

  f32x4 acc[4][4];
#pragma unroll
  for (int a = 0; a < 4; ++a)
#pragma unroll
    for (int bq = 0; bq < 4; ++bq) acc[a][bq] = (f32x4)0.f;

  const unsigned char* Ag = zn8 + (i0 + srow) * 1024 + sh * 16;
  const unsigned char* Bg = zn8 + (j0 + srow) * 1024 + sh * 16;
  const unsigned char* Bsrc = diag ? (const unsigned char*)As : (const unsigned char*)Bs;

#pragma unroll 1
  for (int k0 = 0; k0 < 1024; k0 += 128) {
    __syncthreads();
#pragma unroll
    for (int t = 0; t < 4; ++t)
      __builtin_amdgcn_global_load_lds(
          (const __attribute__((address_space(1))) void*)(Ag + k0 + t * 32),
          (__attribute__((address_space(3))) void*)(As + t * 4096 + (tid & ~63) * 16),
          16, 0, 0);
    if (!diag) {
#pragma unroll
      for (int t = 0; t < 4; ++t)
        __builtin_amdgcn_global_load_lds(
            (const __attribute__((address_space(1))) void*)(Bg + k0 + t * 32),
            (__attribute__((address_space(3))) void*)(Bs + t * 4096 + (tid & ~63) * 16),
            16, 0, 0);
    }
    __syncthreads();
    i32x8 afr[4];
#pragma unroll
    for (int mt = 0; mt < 4; ++mt) {
      int row = wm * 64 + mt * 16 + l4;
      int p0 = (row * 2) ^ ((row >> 2) & 7);
      i32x4 lo = *(const i32x4*)(As + panel + p0 * 16);
      i32x4 hi = *(const i32x4*)(As + panel + (p0 ^ 1) * 16);
      afr[mt] = (i32x8){lo.x, lo.y, lo.z, lo.w, hi.x, hi.y, hi.z, hi.w};
    }
#pragma unroll
    for (int nt = 0; nt < 4; ++nt) {
      int row = wn * 64 + nt * 16 + l4;
      int p0 = (row * 2) ^ ((row >> 2) & 7);
      i32x4 lo = *(const i32x4*)(Bsrc + panel + p0 * 16);
      i32x4 hi = *(const i32x4*)(Bsrc + panel + (p0 ^ 1) * 16);
      i32x8 bfr = (i32x8){lo.x, lo.y, lo.z, lo.w, hi.x, hi.y, hi.z, hi.w};
#pragma unroll
      for (int mt = 0; mt < 4; ++mt)
        acc[mt][nt] = __builtin_amdgcn_mfma_scale_f32_16x16x128_f8f6f4(
            afr[mt], bfr, acc[mt][nt], 0, 0,
            0, 0x7F7F7F7F, 0, 0x7F7F7F7F);
    }
  }

  // epilogue (verified): s = acc*10/256; diag mask; pos; exp;
  // row-sums (lane bits 0-3) + col-sums (lane bits 4-5) -> atomics.
  const float SC = 10.0f / 256.0f;
  float rs[4][4];
  float cs[4] = {0.f, 0.f, 0.f, 0.f};
#pragma unroll
  for (int mt = 0; mt < 4; ++mt)
#pragma unroll
    for (int r = 0; r < 4; ++r) rs[mt][r] = 0.f;
  int ib = i0 + wm * 64 + ((L >> 4) << 2);
  int jb = j0 + wn * 64 + l4;
#pragma unroll
  for (int mt = 0; mt < 4; ++mt)
#pragma unroll
    for (int nt = 0; nt < 4; ++nt) {
      int j = jb + nt * 16;
#pragma unroll
      for (int r = 0; r < 4; ++r) {
        int i = ib + mt * 16 + r;
        float s = acc[mt][nt][r] * SC;
        if (j == (i ^ 4096)) { pos[i] = s; pos[j] = s; }
        float e = (i == j) ? 0.f : __expf(s);
        rs[mt][r] += e;
        if (!diag) cs[nt] += e;
      }
    }
#pragma unroll
  for (int mt = 0; mt < 4; ++mt)
#pragma unroll
    for (int r = 0; r < 4; ++r) {
      float v = rs[mt][r];
      v += __shfl_xor(v, 1); v += __shfl_xor(v, 2);
      v += __shfl_xor(v, 4); v += __shfl_xor(v, 8);
      rs[mt][r] = v;
    }
  int sel = l4;
  float myv = rs[0][0];
#pragma unroll
  for (int mt = 0; mt < 4; ++mt)
#pragma unroll
    for (int r = 0; r < 4; ++r)
      if (sel == mt * 4 + r) myv = rs[mt][r];
  int rowi = i0 + wm * 64 + (sel >> 2) * 16 + ((L >> 4) << 2) + (sel & 3);
  atomicAdd(&sumexp[rowi], myv);
  if (!diag) {
#pragma unroll
    for (int nt = 0; nt < 4; ++nt) {
      float v = cs[nt];
      v += __shfl_xor(v, 16); v += __shfl_xor(v, 32);
      if ((L >> 4) == 0) atomicAdd(&sumexp[jb + nt * 16], v);
    }
  }
}

// -------- finalize: out += mean-partial(log(sumexp) - pos), 16 blocks --------
__global__ __launch_bounds__(512) void finalize_kernel(
    const float* __restrict__ sumexp, const float* __restrict__ pos,
    float* __restrict__ out) {
  int t = threadIdx.x;
  int i = blockIdx.x * 512 + t;
  float s = logf(sumexp[i]) - pos[i];
#pragma unroll
  for (int off = 1; off < 64; off <<= 1) s += __shfl_xor(s, off);
  __shared__ float red[8];
  if ((t & 63) == 0) red[t >> 6] = s;
  __syncthreads();
  if (t == 0) {
    float tot = 0.f;
    for (int k2 = 0; k2 < 8; ++k2) tot += red[k2];
    atomicAdd(out, tot * (1.0f / 8192.0f));
  }
}

extern "C" void kernel_launch(void* const* d_in, const int* in_sizes, int n_in,
                              void* d_out, int out_size, void* d_ws, size_t ws_size,
                              hipStream_t stream) {
  const float* x = (const float*)d_in[0];
  const float* w = (const float*)d_in[1];
  const float* b = (const float*)d_in[2];
  float* out = (float*)d_out;
  char* ws = (char*)d_ws;
  unsigned char* wt8 = (unsigned char*)(ws);
  unsigned char* x8  = (unsigned char*)(ws + 1048576);
  unsigned char* zn8 = (unsigned char*)(ws + 68157440);
  float* sumexp      = (float*)(ws + 84934656);
  float* pos         = (float*)(ws + 84967424);

  prep2_kernel<<<16384, 256, 0, stream>>>(x, x8, sumexp, out);
  wtr_kernel<<<128, 256, 0, stream>>>(w, wt8);
  gemm1qn_kernel<<<256, 512, 0, stream>>>(x8, wt8, b, zn8);
  gemm2_kernel<<<2080, 256, 0, stream>>>(zn8, sumexp, pos);
  finalize_kernel<<<16, 512, 0, stream>>>(sumexp, pos, out);
}

// Round 7
// 163.184 us; speedup vs baseline: 1.2009x; 1.0773x over previous
//
#include <hip/hip_runtime.h>
#include <hip/hip_bf16.h>
#include <stdint.h>

// Problem: B=8192, E=1024, P=512. x:[8192,2048] f32, w:[1024,512] f32, b:[512] f32.
// out: scalar = mean_i( -S[i,i^4096]/T + log(sum_{j!=i} exp(S[i,j]/T)) ),
// S = zn zn^T (symmetric -> upper triangle of 128x128 blocks), T=0.1.
//
// R7: gemm2 moved to MXFP4 (E2M1, cbsz=blgp=4). Same R0 2-barrier structure;
// all per-step costs halve (stage 16KB, LDS 16KB total, 1 ds_read_b128 per
// fragment). zn stored as packed fp4 nibbles zn4[8192][512B], encoded at
// scale 32 (unit-norm rows -> RMS 1.0, clamp at 6 rare). LDS swizzle for
// 64B rows: phys q' = q ^ ((row>>1)&3) -> 2-way banks (free).
// Rest of pipeline = R6 (verified): prep2 + wtr + fused gemm1qn + finalize.
//
// ws layout (bytes):
//   wt8 fp8  [512][1024]    @ 0
//   x8  fp8  [16384][1024]  @ 1048576
//   zn4 fp4  [8192][512]    @ 68157440
//   sumexp f32[8192]        @ 84934656
//   pos    f32[8192]        @ 84967424

typedef __attribute__((ext_vector_type(4))) float f32x4;
typedef __attribute__((ext_vector_type(4))) int i32x4;
typedef __attribute__((ext_vector_type(8))) int i32x8;

// e2m1 (OCP FP4) round-to-nearest encode of |v| with sign; codes:
// 0:0 1:0.5 2:1 3:1.5 4:2 5:3 6:4 7:6
__device__ __forceinline__ unsigned int enc4(float v) {
  unsigned int s = (__float_as_uint(v) >> 28) & 8u;
  float a = fabsf(v);
  unsigned int m;
  if (a < 0.25f) m = 0u;
  else if (a < 0.75f) m = 1u;
  else if (a < 1.25f) m = 2u;
  else if (a < 1.75f) m = 3u;
  else if (a < 2.5f)  m = 4u;
  else if (a < 3.5f)  m = 5u;
  else if (a < 5.0f)  m = 6u;
  else m = 7u;
  return s | m;
}

// ---------------- prep2: x8 = fp8(16*relu(x)); zeros ------------------------
__global__ __launch_bounds__(256) void prep2_kernel(
    const float* __restrict__ x, unsigned char* __restrict__ x8,
    float* __restrict__ sumexp, float* __restrict__ out) {
  int tid = blockIdx.x * 256 + threadIdx.x;
  float4 v = ((const float4*)x)[tid];
  int p = __builtin_amdgcn_cvt_pk_fp8_f32(fmaxf(v.x, 0.f) * 16.f,
                                          fmaxf(v.y, 0.f) * 16.f, 0, false);
  p = __builtin_amdgcn_cvt_pk_fp8_f32(fmaxf(v.z, 0.f) * 16.f,
                                      fmaxf(v.w, 0.f) * 16.f, p, true);
  ((int*)x8)[tid] = p;
  if (tid < 8192) sumexp[tid] = 0.f;
  if (tid == 0) out[0] = 0.f;
}

// ---------------- wtr: wt8[n][k] = fp8(64*w[k][n]) via LDS transpose --------
__global__ __launch_bounds__(256) void wtr_kernel(
    const float* __restrict__ w, unsigned char* __restrict__ wt8) {
  __shared__ unsigned char lt[64][68];
  int b = blockIdx.x, t = threadIdx.x;
  int k0 = (b >> 3) * 64, n0 = (b & 7) * 64;
  int r = t >> 4, c = t & 15;
#pragma unroll
  for (int i = 0; i < 4; ++i) {
    int kl = i * 16 + r;
    float4 v = *(const float4*)&w[(size_t)(k0 + kl) * 512 + n0 + c * 4];
    int q = __builtin_amdgcn_cvt_pk_fp8_f32(v.x * 64.f, v.y * 64.f, 0, false);
    q = __builtin_amdgcn_cvt_pk_fp8_f32(v.z * 64.f, v.w * 64.f, q, true);
    *(int*)&lt[kl][c * 4] = q;
  }
  __syncthreads();
  int nl = t >> 2, ks = t & 3;
  union { unsigned char b8[16]; i32x4 v4; } u;
#pragma unroll
  for (int j = 0; j < 16; ++j) u.b8[j] = lt[ks * 16 + j][nl];
  *(i32x4*)&wt8[(size_t)(n0 + nl) * 1024 + k0 + ks * 16] = u.v4;
}

// -------- gemm1qn: zn4 = fp4(32*normrow(relu(x)@w + b)), fused ---------------
// 256 blocks x 512 thr (8 waves). Block = 64 x8-rows x 512 n-cols = 32 full
// zn rows. Same verified R6 GEMM core; epilogue now encodes e2m1 nibbles
// (scale 32), pairs adjacent cols via shfl_xor(1), even-l4 lanes store bytes.
__global__ __launch_bounds__(512, 2) void gemm1qn_kernel(
    const unsigned char* __restrict__ x8, const unsigned char* __restrict__ wt8,
    const float* __restrict__ bias, unsigned char* __restrict__ zn4) {
  __shared__ unsigned char smem[147456] __attribute__((aligned(16)));
  int i0 = blockIdx.x * 64;
  int tid = threadIdx.x, L = tid & 63, w = tid >> 6;
  int l4 = L & 15, q = L >> 4;

  int sA = tid & 127, pA = tid >> 7;
  int eA = sA ^ ((sA >> 3) & 7);
  int rA = eA >> 1, hA = eA & 1;
  const unsigned char* srcA = x8 + (size_t)(i0 + rA) * 1024 + pA * 32 + hA * 16;
  int e1 = tid ^ ((tid >> 3) & 7);
  int rB = e1 >> 1, hB = e1 & 1;
  const unsigned char* srcB1 = wt8 + (size_t)rB * 1024 + hB * 16;
  const unsigned char* srcB2 = wt8 + (size_t)(rB + 256) * 1024 + hB * 16;

  auto stage = [&](int buf, int k0) {
    __builtin_amdgcn_global_load_lds(
        (const __attribute__((address_space(1))) void*)(srcA + k0),
        (__attribute__((address_space(3))) void*)(smem + buf * 8192 + tid * 16),
        16, 0, 0);
#pragma unroll
    for (int p = 0; p < 4; ++p) {
      __builtin_amdgcn_global_load_lds(
          (const __attribute__((address_space(1))) void*)(srcB1 + k0 + p * 32),
          (__attribute__((address_space(3))) void*)(smem + 16384 + buf * 65536 + p * 16384 + tid * 16),
          16, 0, 0);
      __builtin_amdgcn_global_load_lds(
          (const __attribute__((address_space(1))) void*)(srcB2 + k0 + p * 32),
          (__attribute__((address_space(3))) void*)(smem + 16384 + buf * 65536 + p * 16384 + 8192 + tid * 16),
          16, 0, 0);
    }
  };

  int pAo[4], pBo[4];
#pragma unroll
  for (int mt = 0; mt < 4; ++mt) {
    int r = mt * 16 + l4;
    pAo[mt] = ((r * 2) ^ ((r >> 2) & 7)) * 16;
  }
#pragma unroll
  for (int nt = 0; nt < 4; ++nt) {
    int r = w * 64 + nt * 16 + l4;
    pBo[nt] = ((r * 2) ^ ((r >> 2) & 7)) * 16;
  }

  f32x4 acc[4][4];
#pragma unroll
  for (int a = 0; a < 4; ++a)
#pragma unroll
    for (int bq = 0; bq < 4; ++bq) acc[a][bq] = (f32x4)0.f;

  stage(0, 0);
  __syncthreads();
#pragma unroll 1
  for (int s = 0; s < 8; ++s) {
    if (s < 7) stage((s + 1) & 1, (s + 1) * 128);
    const unsigned char* Ab = smem + (s & 1) * 8192 + q * 2048;
    const unsigned char* Bb = smem + 16384 + (s & 1) * 65536 + q * 16384;
    i32x8 afr[4];
#pragma unroll
    for (int mt = 0; mt < 4; ++mt) {
      i32x4 lo = *(const i32x4*)(Ab + pAo[mt]);
      i32x4 hi = *(const i32x4*)(Ab + (pAo[mt] ^ 16));
      afr[mt] = (i32x8){lo.x, lo.y, lo.z, lo.w, hi.x, hi.y, hi.z, hi.w};
    }
#pragma unroll
    for (int nt = 0; nt < 4; ++nt) {
      i32x4 lo = *(const i32x4*)(Bb + pBo[nt]);
      i32x4 hi = *(const i32x4*)(Bb + (pBo[nt] ^ 16));
      i32x8 bfr = (i32x8){lo.x, lo.y, lo.z, lo.w, hi.x, hi.y, hi.z, hi.w};
#pragma unroll
      for (int mt = 0; mt < 4; ++mt)
        acc[mt][nt] = __builtin_amdgcn_mfma_scale_f32_16x16x128_f8f6f4(
            afr[mt], bfr, acc[mt][nt], 0, 0,
            0, 0x7F7F7F7F, 0, 0x7F7F7F7F);
    }
    __syncthreads();
  }

  // ---- epilogue: z = acc/1024 + bias; row sumsq; fp4 encode at scale 32 ----
  const float SC = 1.0f / 1024.0f;
  float bn[4];
#pragma unroll
  for (int nt = 0; nt < 4; ++nt) bn[nt] = bias[w * 64 + nt * 16 + l4];
  float ssp[4][4];
#pragma unroll
  for (int mt = 0; mt < 4; ++mt)
#pragma unroll
    for (int r = 0; r < 4; ++r) ssp[mt][r] = 0.f;
#pragma unroll
  for (int mt = 0; mt < 4; ++mt)
#pragma unroll
    for (int nt = 0; nt < 4; ++nt)
#pragma unroll
      for (int r = 0; r < 4; ++r) {
        float zv = acc[mt][nt][r] * SC + bn[nt];
        acc[mt][nt][r] = zv;
        ssp[mt][r] += zv * zv;
      }
#pragma unroll
  for (int mt = 0; mt < 4; ++mt)
#pragma unroll
    for (int r = 0; r < 4; ++r) {
      float v = ssp[mt][r];
      v += __shfl_xor(v, 1); v += __shfl_xor(v, 2);
      v += __shfl_xor(v, 4); v += __shfl_xor(v, 8);
      ssp[mt][r] = v;
    }
  float* ssbuf = (float*)smem;          // [64 rows][8 waves], post-barrier alias
  if (l4 == 0) {
#pragma unroll
    for (int mt = 0; mt < 4; ++mt)
#pragma unroll
      for (int r = 0; r < 4; ++r)
        ssbuf[(mt * 16 + q * 4 + r) * 8 + w] = ssp[mt][r];
  }
  __syncthreads();
  float* invbuf = (float*)(smem + 2048);  // [32 zn rows]
  if (tid < 32) {
    float tot = 0.f;
#pragma unroll
    for (int j = 0; j < 8; ++j)
      tot += ssbuf[(2 * tid) * 8 + j] + ssbuf[(2 * tid + 1) * 8 + j];
    invbuf[tid] = 32.f / fmaxf(sqrtf(tot), 1e-8f);
  }
  __syncthreads();
#pragma unroll
  for (int mt = 0; mt < 4; ++mt)
#pragma unroll
    for (int r = 0; r < 4; ++r) {
      int zr = mt * 16 + q * 4 + r;
      float inv = invbuf[zr >> 1];
      int zg = i0 + zr;
      size_t base = (size_t)(zg >> 1) * 512 + (size_t)(zg & 1) * 256;
#pragma unroll
      for (int nt = 0; nt < 4; ++nt) {
        unsigned int n = enc4(acc[mt][nt][r] * inv);
        unsigned int hi = (unsigned int)__shfl_xor((int)n, 1);
        if (!(l4 & 1)) {
          int col = w * 64 + nt * 16 + l4;
          zn4[base + (col >> 1)] = (unsigned char)(n | (hi << 4));
        }
      }
    }
}

// -------- GEMM2 MXFP4 symmetric: 16x16x128 f8f6f4 cbsz=blgp=4, BK=128 --------
// R0 structure verbatim; fp4 halves stage (8KB/matrix/step), LDS (16KB),
// fragment reads (one b128/frag). LDS row = 64B; swizzle: phys slot
// q' = q ^ ((row>>1)&3) -> 16 lanes hit 8 distinct 16B slots (2-way, free).
// Stage: thread t -> phys slots {t, 256+t}: row = t>>2 (+64), logical
// q = (t&3)^((t>>3)&3) (same for both since 64 rows == 0 mod 4 in (row>>1)&3).
// A-frag lane L: m=L&15, k=(L>>4)*32+j (nibble-packed, 16B -> dup both
// halves of the i32x8 operand). C/D: col=L&15, row=(L>>4)*4+reg.
__global__ __launch_bounds__(256, 3) void gemm2_kernel(
    const unsigned char* __restrict__ zn4,
    float* __restrict__ sumexp, float* __restrict__ pos) {
  __shared__ unsigned char As[8192] __attribute__((aligned(16)));
  __shared__ unsigned char Bs[8192] __attribute__((aligned(16)));
  // --- supertile decode (R0-proven bijection over the 2080 triangle blocks) ---
  int g = (blockIdx.x & 7) * 260 + (blockIdx.x >> 3);
  int SI = 0, rem = g;
#pragma unroll 1
  for (SI = 0; SI < 8; ++SI) {
    int rowcnt = 36 + (7 - SI) * 64;
    if (rem < rowcnt) break;
    rem -= rowcnt;
  }
  int bi, bj;
  if (rem < 36) {
    int ti = 0;
    while (rem >= 8 - ti) { rem -= 8 - ti; ++ti; }
    bi = SI * 8 + ti;
    bj = bi + rem;
  } else {
    rem -= 36;
    int SJ = SI + 1 + (rem >> 6);
    int l = rem & 63;
    bi = SI * 8 + (l >> 3);
    bj = SJ * 8 + (l & 7);
  }
  bool diag = (bi == bj);
  int i0 = bi * 128, j0 = bj * 128;

  int tid = threadIdx.x, L = tid & 63, w = tid >> 6;
  int wm = w >> 1, wn = w & 1;
  int l4 = L & 15, q = L >> 4;

  // stage addressing (see header)
  int strow = tid >> 2;
  int sq = (tid & 3) ^ ((tid >> 3) & 3);
  const unsigned char* Ag  = zn4 + (size_t)(i0 + strow) * 512 + sq * 16;
  const unsigned char* Ag2 = Ag + 64 * 512;
  const unsigned char* Bg  = zn4 + (size_t)(j0 + strow) * 512 + sq * 16;
  const unsigned char* Bg2 = Bg + 64 * 512;
  int ldb = (tid & ~63) * 16;

  // fragment read offsets (swizzled)
  int pA[4], pB[4];
#pragma unroll
  for (int mt = 0; mt < 4; ++mt) {
    int r = wm * 64 + mt * 16 + l4;
    pA[mt] = r * 64 + ((q ^ ((r >> 1) & 3)) << 4);
  }
#pragma unroll
  for (int nt = 0; nt < 4; ++nt) {
    int r = wn * 64 + nt * 16 + l4;
    pB[nt] = r * 64 + ((q ^ ((r >> 1) & 3)) << 4);
  }

  f32x4 acc[4][4];
#pragma unroll
  for (int a = 0; a < 4; ++a)
#pragma unroll
    for (int bq = 0; bq < 4; ++bq) acc[a][bq] = (f32x4)0.f;

  const unsigned char* Bsrc = diag ? (const unsigned char*)As : (const unsigned char*)Bs;

#pragma unroll 1
  for (int koff = 0; koff < 512; koff += 64) {   // koff = k0/2 bytes
    __syncthreads();
    __builtin_amdgcn_global_load_lds(
        (const __attribute__((address_space(1))) void*)(Ag + koff),
        (__attribute__((address_space(3))) void*)(As + ldb), 16, 0, 0);
    __builtin_amdgcn_global_load_lds(
        (const __attribute__((address_space(1))) void*)(Ag2 + koff),
        (__attribute__((address_space(3))) void*)(As + 4096 + ldb), 16, 0, 0);
    if (!diag) {
      __builtin_amdgcn_global_load_lds(
          (const __attribute__((address_space(1))) void*)(Bg + koff),
          (__attribute__((address_space(3))) void*)(Bs + ldb), 16, 0, 0);
      __builtin_amdgcn_global_load_lds(
          (const __attribute__((address_space(1))) void*)(Bg2 + koff),
          (__attribute__((address_space(3))) void*)(Bs + 4096 + ldb), 16, 0, 0);
    }
    __syncthreads();
    i32x4 a4[4];
#pragma unroll
    for (int mt = 0; mt < 4; ++mt) a4[mt] = *(const i32x4*)(As + pA[mt]);
#pragma unroll
    for (int nt = 0; nt < 4; ++nt) {
      i32x4 b4 = *(const i32x4*)(Bsrc + pB[nt]);
      i32x8 bfr = (i32x8){b4.x, b4.y, b4.z, b4.w, b4.x, b4.y, b4.z, b4.w};
#pragma unroll
      for (int mt = 0; mt < 4; ++mt) {
        i32x8 afr = (i32x8){a4[mt].x, a4[mt].y, a4[mt].z, a4[mt].w,
                            a4[mt].x, a4[mt].y, a4[mt].z, a4[mt].w};
        acc[mt][nt] = __builtin_amdgcn_mfma_scale_f32_16x16x128_f8f6f4(
            afr, bfr, acc[mt][nt], 4, 4,
            0, 0x7F7F7F7F, 0, 0x7F7F7F7F);
      }
    }
  }

  // epilogue (verified): s = acc*10/1024 (scale-32 fp4); diag mask; pos; exp;
  // row-sums (lane bits 0-3) + col-sums (lane bits 4-5) -> atomics.
  const float SC = 10.0f / 1024.0f;
  float rs[4][4];
  float cs[4] = {0.f, 0.f, 0.f, 0.f};
#pragma unroll
  for (int mt = 0; mt < 4; ++mt)
#pragma unroll
    for (int r = 0; r < 4; ++r) rs[mt][r] = 0.f;
  int ib = i0 + wm * 64 + (q << 2);
  int jb = j0 + wn * 64 + l4;
#pragma unroll
  for (int mt = 0; mt < 4; ++mt)
#pragma unroll
    for (int nt = 0; nt < 4; ++nt) {
      int j = jb + nt * 16;
#pragma unroll
      for (int r = 0; r < 4; ++r) {
        int i = ib + mt * 16 + r;
        float s = acc[mt][nt][r] * SC;
        if (j == (i ^ 4096)) { pos[i] = s; pos[j] = s; }
        float e = (i == j) ? 0.f : __expf(s);
        rs[mt][r] += e;
        if (!diag) cs[nt] += e;
      }
    }
#pragma unroll
  for (int mt = 0; mt < 4; ++mt)
#pragma unroll
    for (int r = 0; r < 4; ++r) {
      float v = rs[mt][r];
      v += __shfl_xor(v, 1); v += __shfl_xor(v, 2);
      v += __shfl_xor(v, 4); v += __shfl_xor(v, 8);
      rs[mt][r] = v;
    }
  int sel = l4;
  float myv = rs[0][0];
#pragma unroll
  for (int mt = 0; mt < 4; ++mt)
#pragma unroll
    for (int r = 0; r < 4; ++r)
      if (sel == mt * 4 + r) myv = rs[mt][r];
  int rowi = i0 + wm * 64 + (sel >> 2) * 16 + (q << 2) + (sel & 3);
  atomicAdd(&sumexp[rowi], myv);
  if (!diag) {
#pragma unroll
    for (int nt = 0; nt < 4; ++nt) {
      float v = cs[nt];
      v += __shfl_xor(v, 16); v += __shfl_xor(v, 32);
      if (q == 0) atomicAdd(&sumexp[jb + nt * 16], v);
    }
  }
}

// -------- finalize: out += mean-partial(log(sumexp) - pos), 16 blocks --------
__global__ __launch_bounds__(512) void finalize_kernel(
    const float* __restrict__ sumexp, const float* __restrict__ pos,
    float* __restrict__ out) {
  int t = threadIdx.x;
  int i = blockIdx.x * 512 + t;
  float s = logf(sumexp[i]) - pos[i];
#pragma unroll
  for (int off = 1; off < 64; off <<= 1) s += __shfl_xor(s, off);
  __shared__ float red[8];
  if ((t & 63) == 0) red[t >> 6] = s;
  __syncthreads();
  if (t == 0) {
    float tot = 0.f;
    for (int k2 = 0; k2 < 8; ++k2) tot += red[k2];
    atomicAdd(out, tot * (1.0f / 8192.0f));
  }
}

extern "C" void kernel_launch(void* const* d_in, const int* in_sizes, int n_in,
                              void* d_out, int out_size, void* d_ws, size_t ws_size,
                              hipStream_t stream) {
  const float* x = (const float*)d_in[0];
  const float* w = (const float*)d_in[1];
  const float* b = (const float*)d_in[2];
  float* out = (float*)d_out;
  char* ws = (char*)d_ws;
  unsigned char* wt8 = (unsigned char*)(ws);
  unsigned char* x8  = (unsigned char*)(ws + 1048576);
  unsigned char* zn4 = (unsigned char*)(ws + 68157440);
  float* sumexp      = (float*)(ws + 84934656);
  float* pos         = (float*)(ws + 84967424);

  prep2_kernel<<<16384, 256, 0, stream>>>(x, x8, sumexp, out);
  wtr_kernel<<<128, 256, 0, stream>>>(w, wt8);
  gemm1qn_kernel<<<256, 512, 0, stream>>>(x8, wt8, b, zn4);
  gemm2_kernel<<<2080, 256, 0, stream>>>(zn4, sumexp, pos);
  finalize_kernel<<<16, 512, 0, stream>>>(sumexp, pos, out);
}

// Round 8
// 156.513 us; speedup vs baseline: 1.2521x; 1.0426x over previous
//
#include <hip/hip_runtime.h>
#include <hip/hip_bf16.h>
#include <stdint.h>

// Problem: B=8192, E=1024, P=512. x:[8192,2048] f32, w:[1024,512] f32, b:[512] f32.
// out: scalar = mean_i( -S[i,i^4096]/T + log(sum_{j!=i} exp(S[i,j]/T)) ),
// S = zn zn^T (symmetric -> upper triangle of 128x128 blocks), T=0.1.
//
// R8: prep2 fused INTO gemm1qn (A-path reads x f32 directly, relu+fp8
// quantize in regs, ds_write_b128 into the same swizzled LDS layout;
// bit-identical values to prep2's). Kills a 80 MB HBM round-trip kernel.
// wtr picks up the sumexp/out zeroing. gemm2 = R7 MXFP4 verbatim (proven).
// Pipeline: wtr -> gemm1qn(fused) -> gemm2(fp4) -> finalize  (4 launches).
//
// ws layout (bytes):
//   wt8 fp8  [512][1024]    @ 0
//   zn4 fp4  [8192][512]    @ 68157440
//   sumexp f32[8192]        @ 84934656
//   pos    f32[8192]        @ 84967424

typedef __attribute__((ext_vector_type(4))) float f32x4;
typedef __attribute__((ext_vector_type(4))) int i32x4;
typedef __attribute__((ext_vector_type(8))) int i32x8;

// e2m1 (OCP FP4) round-to-nearest encode of |v| with sign; codes:
// 0:0 1:0.5 2:1 3:1.5 4:2 5:3 6:4 7:6
__device__ __forceinline__ unsigned int enc4(float v) {
  unsigned int s = (__float_as_uint(v) >> 28) & 8u;
  float a = fabsf(v);
  unsigned int m;
  if (a < 0.25f) m = 0u;
  else if (a < 0.75f) m = 1u;
  else if (a < 1.25f) m = 2u;
  else if (a < 1.75f) m = 3u;
  else if (a < 2.5f)  m = 4u;
  else if (a < 3.5f)  m = 5u;
  else if (a < 5.0f)  m = 6u;
  else m = 7u;
  return s | m;
}

// ---------------- wtr: wt8[n][k] = fp8(64*w[k][n]) via LDS transpose --------
// + zeros sumexp/out (absorbed from prep2).
__global__ __launch_bounds__(256) void wtr_kernel(
    const float* __restrict__ w, unsigned char* __restrict__ wt8,
    float* __restrict__ sumexp, float* __restrict__ out) {
  __shared__ unsigned char lt[64][68];
  int b = blockIdx.x, t = threadIdx.x;
  int gt = b * 256 + t;
  if (gt < 8192) sumexp[gt] = 0.f;
  if (gt == 0) out[0] = 0.f;
  int k0 = (b >> 3) * 64, n0 = (b & 7) * 64;
  int r = t >> 4, c = t & 15;
#pragma unroll
  for (int i = 0; i < 4; ++i) {
    int kl = i * 16 + r;
    float4 v = *(const float4*)&w[(size_t)(k0 + kl) * 512 + n0 + c * 4];
    int q = __builtin_amdgcn_cvt_pk_fp8_f32(v.x * 64.f, v.y * 64.f, 0, false);
    q = __builtin_amdgcn_cvt_pk_fp8_f32(v.z * 64.f, v.w * 64.f, q, true);
    *(int*)&lt[kl][c * 4] = q;
  }
  __syncthreads();
  int nl = t >> 2, ks = t & 3;
  union { unsigned char b8[16]; i32x4 v4; } u;
#pragma unroll
  for (int j = 0; j < 16; ++j) u.b8[j] = lt[ks * 16 + j][nl];
  *(i32x4*)&wt8[(size_t)(n0 + nl) * 1024 + k0 + ks * 16] = u.v4;
}

// -------- gemm1qn: zn4 = fp4(32*normrow(relu(x)@w + b)), fully fused ---------
// 256 blocks x 512 thr (8 waves). Block = 64 a-rows x 512 n-cols = 32 full
// zn rows (a-row g = half (g&1) of x row g>>1; x linear = g*1024 floats).
// A-path FUSED: per K-step each thread loads 16 f32 (4 float4, contiguous
// 64 B), relu*16 -> fp8 (bit-identical to old prep2), ds_write_b128 to the
// swizzled slot: thread (ra=tid>>3, kq=tid&7) -> panel kq>>1 (2 KB), slot
// S = ((ra*2)^((ra>>2)&7))^(kq&1)  [involution-verified vs read p0].
// Loads issued at step top, consumed after MFMA (T14 latency hiding).
// B staged via global_load_lds from wt8 (unchanged, verified).
// Epilogue: z=acc/1024+bias, row sumsq, e2m1 encode at scale 32 (R7 path).
// A-frag lane L: m=L&15, k=(L>>4)*32+j. C/D: col=L&15, row=(L>>4)*4+reg.
__global__ __launch_bounds__(512, 2) void gemm1qn_kernel(
    const float* __restrict__ x, const unsigned char* __restrict__ wt8,
    const float* __restrict__ bias, unsigned char* __restrict__ zn4) {
  __shared__ unsigned char smem[147456] __attribute__((aligned(16)));
  int i0 = blockIdx.x * 64;
  int tid = threadIdx.x, L = tid & 63, w = tid >> 6;
  int l4 = L & 15, q = L >> 4;

  // ---- fused A-staging decode ----
  int ra = tid >> 3, kq = tid & 7;
  int Sslot = ((ra * 2) ^ ((ra >> 2) & 7)) ^ (kq & 1);
  int Aoff = (kq >> 1) * 2048 + Sslot * 16;
  const float* xq = x + (size_t)(i0 + ra) * 1024 + kq * 16;

  // ---- B staging decode (gload_lds, unchanged) ----
  int e1 = tid ^ ((tid >> 3) & 7);
  int rB = e1 >> 1, hB = e1 & 1;
  const unsigned char* srcB1 = wt8 + (size_t)rB * 1024 + hB * 16;
  const unsigned char* srcB2 = wt8 + (size_t)(rB + 256) * 1024 + hB * 16;

  auto stageB = [&](int buf, int k0) {
#pragma unroll
    for (int p = 0; p < 4; ++p) {
      __builtin_amdgcn_global_load_lds(
          (const __attribute__((address_space(1))) void*)(srcB1 + k0 + p * 32),
          (__attribute__((address_space(3))) void*)(smem + 16384 + buf * 65536 + p * 16384 + tid * 16),
          16, 0, 0);
      __builtin_amdgcn_global_load_lds(
          (const __attribute__((address_space(1))) void*)(srcB2 + k0 + p * 32),
          (__attribute__((address_space(3))) void*)(smem + 16384 + buf * 65536 + p * 16384 + 8192 + tid * 16),
          16, 0, 0);
    }
  };

  auto writeA = [&](int buf, const float4* xv) {
    int pk[4];
#pragma unroll
    for (int j = 0; j < 4; ++j) {
      int p = __builtin_amdgcn_cvt_pk_fp8_f32(fmaxf(xv[j].x, 0.f) * 16.f,
                                              fmaxf(xv[j].y, 0.f) * 16.f, 0, false);
      p = __builtin_amdgcn_cvt_pk_fp8_f32(fmaxf(xv[j].z, 0.f) * 16.f,
                                          fmaxf(xv[j].w, 0.f) * 16.f, p, true);
      pk[j] = p;
    }
    *(i32x4*)(smem + buf * 8192 + Aoff) = (i32x4){pk[0], pk[1], pk[2], pk[3]};
  };

  // ---- read-side swizzled offsets (unchanged) ----
  int pAo[4], pBo[4];
#pragma unroll
  for (int mt = 0; mt < 4; ++mt) {
    int r = mt * 16 + l4;
    pAo[mt] = ((r * 2) ^ ((r >> 2) & 7)) * 16;
  }
#pragma unroll
  for (int nt = 0; nt < 4; ++nt) {
    int r = w * 64 + nt * 16 + l4;
    pBo[nt] = ((r * 2) ^ ((r >> 2) & 7)) * 16;
  }

  f32x4 acc[4][4];
#pragma unroll
  for (int a = 0; a < 4; ++a)
#pragma unroll
    for (int bq = 0; bq < 4; ++bq) acc[a][bq] = (f32x4)0.f;

  // prologue: stage K-tile 0
  float4 xv[4];
#pragma unroll
  for (int j = 0; j < 4; ++j) xv[j] = *(const float4*)(xq + j * 4);
  writeA(0, xv);
  stageB(0, 0);
  __syncthreads();

#pragma unroll 1
  for (int s = 0; s < 8; ++s) {
    if (s < 7) {
#pragma unroll
      for (int j = 0; j < 4; ++j)
        xv[j] = *(const float4*)(xq + (s + 1) * 128 + j * 4);
      stageB((s + 1) & 1, (s + 1) * 128);
    }
    const unsigned char* Ab = smem + (s & 1) * 8192 + q * 2048;
    const unsigned char* Bb = smem + 16384 + (s & 1) * 65536 + q * 16384;
    i32x8 afr[4];
#pragma unroll
    for (int mt = 0; mt < 4; ++mt) {
      i32x4 lo = *(const i32x4*)(Ab + pAo[mt]);
      i32x4 hi = *(const i32x4*)(Ab + (pAo[mt] ^ 16));
      afr[mt] = (i32x8){lo.x, lo.y, lo.z, lo.w, hi.x, hi.y, hi.z, hi.w};
    }
#pragma unroll
    for (int nt = 0; nt < 4; ++nt) {
      i32x4 lo = *(const i32x4*)(Bb + pBo[nt]);
      i32x4 hi = *(const i32x4*)(Bb + (pBo[nt] ^ 16));
      i32x8 bfr = (i32x8){lo.x, lo.y, lo.z, lo.w, hi.x, hi.y, hi.z, hi.w};
#pragma unroll
      for (int mt = 0; mt < 4; ++mt)
        acc[mt][nt] = __builtin_amdgcn_mfma_scale_f32_16x16x128_f8f6f4(
            afr[mt], bfr, acc[mt][nt], 0, 0,
            0, 0x7F7F7F7F, 0, 0x7F7F7F7F);
    }
    if (s < 7) writeA((s + 1) & 1, xv);
    __syncthreads();
  }

  // ---- epilogue: z = acc/1024 + bias; row sumsq; fp4 encode at scale 32 ----
  const float SC = 1.0f / 1024.0f;
  float bn[4];
#pragma unroll
  for (int nt = 0; nt < 4; ++nt) bn[nt] = bias[w * 64 + nt * 16 + l4];
  float ssp[4][4];
#pragma unroll
  for (int mt = 0; mt < 4; ++mt)
#pragma unroll
    for (int r = 0; r < 4; ++r) ssp[mt][r] = 0.f;
#pragma unroll
  for (int mt = 0; mt < 4; ++mt)
#pragma unroll
    for (int nt = 0; nt < 4; ++nt)
#pragma unroll
      for (int r = 0; r < 4; ++r) {
        float zv = acc[mt][nt][r] * SC + bn[nt];
        acc[mt][nt][r] = zv;
        ssp[mt][r] += zv * zv;
      }
#pragma unroll
  for (int mt = 0; mt < 4; ++mt)
#pragma unroll
    for (int r = 0; r < 4; ++r) {
      float v = ssp[mt][r];
      v += __shfl_xor(v, 1); v += __shfl_xor(v, 2);
      v += __shfl_xor(v, 4); v += __shfl_xor(v, 8);
      ssp[mt][r] = v;
    }
  float* ssbuf = (float*)smem;          // [64 rows][8 waves], post-barrier alias
  if (l4 == 0) {
#pragma unroll
    for (int mt = 0; mt < 4; ++mt)
#pragma unroll
      for (int r = 0; r < 4; ++r)
        ssbuf[(mt * 16 + q * 4 + r) * 8 + w] = ssp[mt][r];
  }
  __syncthreads();
  float* invbuf = (float*)(smem + 2048);  // [32 zn rows]
  if (tid < 32) {
    float tot = 0.f;
#pragma unroll
    for (int j = 0; j < 8; ++j)
      tot += ssbuf[(2 * tid) * 8 + j] + ssbuf[(2 * tid + 1) * 8 + j];
    invbuf[tid] = 32.f / fmaxf(sqrtf(tot), 1e-8f);
  }
  __syncthreads();
#pragma unroll
  for (int mt = 0; mt < 4; ++mt)
#pragma unroll
    for (int r = 0; r < 4; ++r) {
      int zr = mt * 16 + q * 4 + r;
      float inv = invbuf[zr >> 1];
      int zg = i0 + zr;
      size_t base = (size_t)(zg >> 1) * 512 + (size_t)(zg & 1) * 256;
#pragma unroll
      for (int nt = 0; nt < 4; ++nt) {
        unsigned int n = enc4(acc[mt][nt][r] * inv);
        unsigned int hi = (unsigned int)__shfl_xor((int)n, 1);
        if (!(l4 & 1)) {
          int col = w * 64 + nt * 16 + l4;
          zn4[base + (col >> 1)] = (unsigned char)(n | (hi << 4));
        }
      }
    }
}

// -------- GEMM2 MXFP4 symmetric: 16x16x128 f8f6f4 cbsz=blgp=4 (R7 verbatim) --
__global__ __launch_bounds__(256, 3) void gemm2_kernel(
    const unsigned char* __restrict__ zn4,
    float* __restrict__ sumexp, float* __restrict__ pos) {
  __shared__ unsigned char As[8192] __attribute__((aligned(16)));
  __shared__ unsigned char Bs[8192] __attribute__((aligned(16)));
  int g = (blockIdx.x & 7) * 260 + (blockIdx.x >> 3);
  int SI = 0, rem = g;
#pragma unroll 1
  for (SI = 0; SI < 8; ++SI) {
    int rowcnt = 36 + (7 - SI) * 64;
    if (rem < rowcnt) break;
    rem -= rowcnt;
  }
  int bi, bj;
  if (rem < 36) {
    int ti = 0;
    while (rem >= 8 - ti) { rem -= 8 - ti; ++ti; }
    bi = SI * 8 + ti;
    bj = bi + rem;
  } else {
    rem -= 36;
    int SJ = SI + 1 + (rem >> 6);
    int l = rem & 63;
    bi = SI * 8 + (l >> 3);
    bj = SJ * 8 + (l & 7);
  }
  bool diag = (bi == bj);
  int i0 = bi * 128, j0 = bj * 128;

  int tid = threadIdx.x, L = tid & 63, w = tid >> 6;
  int wm = w >> 1, wn = w & 1;
  int l4 = L & 15, q = L >> 4;

  int strow = tid >> 2;
  int sq = (tid & 3) ^ ((tid >> 3) & 3);
  const unsigned char* Ag  = zn4 + (size_t)(i0 + strow) * 512 + sq * 16;
  const unsigned char* Ag2 = Ag + 64 * 512;
  const unsigned char* Bg  = zn4 + (size_t)(j0 + strow) * 512 + sq * 16;
  const unsigned char* Bg2 = Bg + 64 * 512;
  int ldb = (tid & ~63) * 16;

  int pA[4], pB[4];
#pragma unroll
  for (int mt = 0; mt < 4; ++mt) {
    int r = wm * 64 + mt * 16 + l4;
    pA[mt] = r * 64 + ((q ^ ((r >> 1) & 3)) << 4);
  }
#pragma unroll
  for (int nt = 0; nt < 4; ++nt) {
    int r = wn * 64 + nt * 16 + l4;
    pB[nt] = r * 64 + ((q ^ ((r >> 1) & 3)) << 4);
  }

  f32x4 acc[4][4];
#pragma unroll
  for (int a = 0; a < 4; ++a)
#pragma unroll
    for (int bq = 0; bq < 4; ++bq) acc[a][bq] = (f32x4)0.f;

  const unsigned char* Bsrc = diag ? (const unsigned char*)As : (const unsigned char*)Bs;

#pragma unroll 1
  for (int koff = 0; koff < 512; koff += 64) {
    __syncthreads();
    __builtin_amdgcn_global_load_lds(
        (const __attribute__((address_space(1))) void*)(Ag + koff),
        (__attribute__((address_space(3))) void*)(As + ldb), 16, 0, 0);
    __builtin_amdgcn_global_load_lds(
        (const __attribute__((address_space(1))) void*)(Ag2 + koff),
        (__attribute__((address_space(3))) void*)(As + 4096 + ldb), 16, 0, 0);
    if (!diag) {
      __builtin_amdgcn_global_load_lds(
          (const __attribute__((address_space(1))) void*)(Bg + koff),
          (__attribute__((address_space(3))) void*)(Bs + ldb), 16, 0, 0);
      __builtin_amdgcn_global_load_lds(
          (const __attribute__((address_space(1))) void*)(Bg2 + koff),
          (__attribute__((address_space(3))) void*)(Bs + 4096 + ldb), 16, 0, 0);
    }
    __syncthreads();
    i32x4 a4[4];
#pragma unroll
    for (int mt = 0; mt < 4; ++mt) a4[mt] = *(const i32x4*)(As + pA[mt]);
#pragma unroll
    for (int nt = 0; nt < 4; ++nt) {
      i32x4 b4 = *(const i32x4*)(Bsrc + pB[nt]);
      i32x8 bfr = (i32x8){b4.x, b4.y, b4.z, b4.w, b4.x, b4.y, b4.z, b4.w};
#pragma unroll
      for (int mt = 0; mt < 4; ++mt) {
        i32x8 afr = (i32x8){a4[mt].x, a4[mt].y, a4[mt].z, a4[mt].w,
                            a4[mt].x, a4[mt].y, a4[mt].z, a4[mt].w};
        acc[mt][nt] = __builtin_amdgcn_mfma_scale_f32_16x16x128_f8f6f4(
            afr, bfr, acc[mt][nt], 4, 4,
            0, 0x7F7F7F7F, 0, 0x7F7F7F7F);
      }
    }
  }

  const float SC = 10.0f / 1024.0f;
  float rs[4][4];
  float cs[4] = {0.f, 0.f, 0.f, 0.f};
#pragma unroll
  for (int mt = 0; mt < 4; ++mt)
#pragma unroll
    for (int r = 0; r < 4; ++r) rs[mt][r] = 0.f;
  int ib = i0 + wm * 64 + (q << 2);
  int jb = j0 + wn * 64 + l4;
#pragma unroll
  for (int mt = 0; mt < 4; ++mt)
#pragma unroll
    for (int nt = 0; nt < 4; ++nt) {
      int j = jb + nt * 16;
#pragma unroll
      for (int r = 0; r < 4; ++r) {
        int i = ib + mt * 16 + r;
        float s = acc[mt][nt][r] * SC;
        if (j == (i ^ 4096)) { pos[i] = s; pos[j] = s; }
        float e = (i == j) ? 0.f : __expf(s);
        rs[mt][r] += e;
        if (!diag) cs[nt] += e;
      }
    }
#pragma unroll
  for (int mt = 0; mt < 4; ++mt)
#pragma unroll
    for (int r = 0; r < 4; ++r) {
      float v = rs[mt][r];
      v += __shfl_xor(v, 1); v += __shfl_xor(v, 2);
      v += __shfl_xor(v, 4); v += __shfl_xor(v, 8);
      rs[mt][r] = v;
    }
  int sel = l4;
  float myv = rs[0][0];
#pragma unroll
  for (int mt = 0; mt < 4; ++mt)
#pragma unroll
    for (int r = 0; r < 4; ++r)
      if (sel == mt * 4 + r) myv = rs[mt][r];
  int rowi = i0 + wm * 64 + (sel >> 2) * 16 + (q << 2) + (sel & 3);
  atomicAdd(&sumexp[rowi], myv);
  if (!diag) {
#pragma unroll
    for (int nt = 0; nt < 4; ++nt) {
      float v = cs[nt];
      v += __shfl_xor(v, 16); v += __shfl_xor(v, 32);
      if (q == 0) atomicAdd(&sumexp[jb + nt * 16], v);
    }
  }
}

// -------- finalize: out += mean-partial(log(sumexp) - pos), 16 blocks --------
__global__ __launch_bounds__(512) void finalize_kernel(
    const float* __restrict__ sumexp, const float* __restrict__ pos,
    float* __restrict__ out) {
  int t = threadIdx.x;
  int i = blockIdx.x * 512 + t;
  float s = logf(sumexp[i]) - pos[i];
#pragma unroll
  for (int off = 1; off < 64; off <<= 1) s += __shfl_xor(s, off);
  __shared__ float red[8];
  if ((t & 63) == 0) red[t >> 6] = s;
  __syncthreads();
  if (t == 0) {
    float tot = 0.f;
    for (int k2 = 0; k2 < 8; ++k2) tot += red[k2];
    atomicAdd(out, tot * (1.0f / 8192.0f));
  }
}

extern "C" void kernel_launch(void* const* d_in, const int* in_sizes, int n_in,
                              void* d_out, int out_size, void* d_ws, size_t ws_size,
                              hipStream_t stream) {
  const float* x = (const float*)d_in[0];
  const float* w = (const float*)d_in[1];
  const float* b = (const float*)d_in[2];
  float* out = (float*)d_out;
  char* ws = (char*)d_ws;
  unsigned char* wt8 = (unsigned char*)(ws);
  unsigned char* zn4 = (unsigned char*)(ws + 68157440);
  float* sumexp      = (float*)(ws + 84934656);
  float* pos         = (float*)(ws + 84967424);

  wtr_kernel<<<128, 256, 0, stream>>>(w, wt8, sumexp, out);
  gemm1qn_kernel<<<256, 512, 0, stream>>>(x, wt8, b, zn4);
  gemm2_kernel<<<2080, 256, 0, stream>>>(zn4, sumexp, pos);
  finalize_kernel<<<16, 512, 0, stream>>>(sumexp, pos, out);
}